// Round 14
// baseline (236.418 us; speedup 1.0000x reference)
//
#include <hip/hip_runtime.h>
#include <math.h>

#define NROWS 1024      // B*P
#define K1    12544
#define REP   1024
#define NDET  2048      // P*(C-1)
#define DETS  100
#define BBOX_CLIP_F 4.135166556742356f

typedef __attribute__((ext_vector_type(8))) short bf16x8;
typedef __attribute__((ext_vector_type(4))) float f32x4;

__device__ __forceinline__ unsigned short rne_bf16(float x) {
  unsigned u = __float_as_uint(x);
  u += 0x7fffu + ((u >> 16) & 1u);
  return (unsigned short)(u >> 16);
}
__device__ __forceinline__ float bf16f(unsigned short h) {
  return __uint_as_float(((unsigned)h) << 16);
}
// chunk swizzle: slot s of row r lives at chunk r*4 + SWZ(r,s) within an 8KB tile
__device__ __forceinline__ int swz(int r, int s) {
  return s ^ (r & 3) ^ ((r >> 2) & 3);
}
__device__ __forceinline__ void gload16(const void* g, void* lds) {
  __builtin_amdgcn_global_load_lds(
      (const __attribute__((address_space(1))) unsigned int*)g,
      (__attribute__((address_space(3))) unsigned int*)lds, 16, 0, 0);
}

// ---------- fused pack: W1, W2 (transpose-pack), A (row-pack), Wt (25x1024) ----------
// grid = 12544 (W1) + 1024 (W2) + 6272 (A) + 100 (Wt) = 19940 blocks x 256
__global__ __launch_bounds__(256) void pack_fused(
    const float* __restrict__ X, const float* __restrict__ W1,
    const float* __restrict__ W2, const float* __restrict__ Wc,
    const float* __restrict__ Wb,
    unsigned short* __restrict__ Ahp, unsigned short* __restrict__ Alp,
    unsigned short* __restrict__ W1h, unsigned short* __restrict__ W1l,
    unsigned short* __restrict__ W2h, unsigned short* __restrict__ W2l,
    float* __restrict__ Wt) {
  __shared__ unsigned short th[32 * 36], tl[32 * 36];
  const int id = blockIdx.x;
  const int t = threadIdx.x;
  if (id < 13568) {
    // ---- pack_b for W1 (nKB=392) or W2 (nKB=32) ----
    const float* W;
    unsigned short *Oh, *Ol;
    int nKB, kb, n0;
    if (id < 12544) { W = W1; Oh = W1h; Ol = W1l; nKB = 392; kb = id % 392; n0 = (id / 392) * 32; }
    else { const int r2 = id - 12544; W = W2; Oh = W2h; Ol = W2l; nKB = 32; kb = r2 % 32; n0 = (r2 / 32) * 32; }
    const int r = t >> 3, c4 = (t & 7) << 2;          // r = k_local
    float4 v = *(const float4*)&W[(size_t)(kb * 32 + r) * REP + n0 + c4];
    float fv[4] = {v.x, v.y, v.z, v.w};
#pragma unroll
    for (int j = 0; j < 4; ++j) {
      unsigned short h = rne_bf16(fv[j]);
      th[(c4 + j) * 36 + r] = h;
      tl[(c4 + j) * 36 + r] = rne_bf16(fv[j] - bf16f(h));
    }
    __syncthreads();
    const int half = t >> 7;                           // 0 -> h, 1 -> l
    const int n_loc = (t & 127) >> 2, slot = t & 3;
    const unsigned short* src = (half ? tl : th) + n_loc * 36 + slot * 8;
    ushort4 u0 = *(const ushort4*)src;
    ushort4 u1 = *(const ushort4*)(src + 4);
    const int n = n0 + n_loc, rb = n >> 7, rr = n & 127;
    size_t chunk = ((size_t)(rb * nKB + kb)) * 512 + rr * 4 + swz(rr, slot);
    unsigned short* dst = (half ? Ol : Oh) + chunk * 8;
    *(ushort4*)dst = u0;
    *(ushort4*)(dst + 4) = u1;
  } else if (id < 19840) {
    // ---- pack_a for X (nKB=392) ----
    const int r_ = id - 13568;
    const int kb = r_ % 392;
    const int row = (r_ / 392) * 64 + (t >> 2);
    const int slot = t & 3;
    const float* p = X + (size_t)row * K1 + kb * 32 + slot * 8;
    float4 f0 = *(const float4*)p;
    float4 f1 = *(const float4*)(p + 4);
    float fv[8] = {f0.x, f0.y, f0.z, f0.w, f1.x, f1.y, f1.z, f1.w};
    unsigned short hh[8], ll[8];
#pragma unroll
    for (int j = 0; j < 8; ++j) {
      hh[j] = rne_bf16(fv[j]);
      ll[j] = rne_bf16(fv[j] - bf16f(hh[j]));
    }
    const int rb = row >> 7, rr = row & 127;
    size_t chunk = ((size_t)(rb * 392 + kb)) * 512 + rr * 4 + swz(rr, slot);
    unsigned short* dh = Ahp + chunk * 8;
    unsigned short* dl = Alp + chunk * 8;
    *(ushort4*)dh = make_ushort4(hh[0], hh[1], hh[2], hh[3]);
    *(ushort4*)(dh + 4) = make_ushort4(hh[4], hh[5], hh[6], hh[7]);
    *(ushort4*)dl = make_ushort4(ll[0], ll[1], ll[2], ll[3]);
    *(ushort4*)(dl + 4) = make_ushort4(ll[4], ll[5], ll[6], ll[7]);
  } else {
    // ---- pack_w25: Wt[25][1024] from Wc[1024][5], Wb[1024][20] ----
    const int i = (id - 19840) * 256 + t;
    if (i < 25 * 1024) {
      const int o = i >> 10, k = i & 1023;
      Wt[i] = (o < 5) ? Wc[(size_t)k * 5 + o] : Wb[(size_t)k * 20 + (o - 5)];
    }
  }
}

// ---------- standalone packs (fallback path 1) ----------
__global__ __launch_bounds__(256) void pack_b(
    const float* __restrict__ W, unsigned short* __restrict__ Oh,
    unsigned short* __restrict__ Ol, int nKB) {
  __shared__ unsigned short th[32 * 36], tl[32 * 36];
  const int kb = blockIdx.x, n0 = blockIdx.y * 32;
  const int t = threadIdx.x;
  const int r = t >> 3, c4 = (t & 7) << 2;
  float4 v = *(const float4*)&W[(size_t)(kb * 32 + r) * REP + n0 + c4];
  float fv[4] = {v.x, v.y, v.z, v.w};
#pragma unroll
  for (int j = 0; j < 4; ++j) {
    unsigned short h = rne_bf16(fv[j]);
    th[(c4 + j) * 36 + r] = h;
    tl[(c4 + j) * 36 + r] = rne_bf16(fv[j] - bf16f(h));
  }
  __syncthreads();
  const int half = t >> 7;
  const int n_loc = (t & 127) >> 2, slot = t & 3;
  const unsigned short* src = (half ? tl : th) + n_loc * 36 + slot * 8;
  ushort4 u0 = *(const ushort4*)src;
  ushort4 u1 = *(const ushort4*)(src + 4);
  const int n = n0 + n_loc, rb = n >> 7, rr = n & 127;
  size_t chunk = ((size_t)(rb * nKB + kb)) * 512 + rr * 4 + swz(rr, slot);
  unsigned short* dst = (half ? Ol : Oh) + chunk * 8;
  *(ushort4*)dst = u0;
  *(ushort4*)(dst + 4) = u1;
}

// ---------- MFMA GEMM, 256x128 tile, both operands pre-packed: T[z] = A @ B ----------
// 4 waves x (128x64 via 8x4 16x16x32 frags), BK=32, splitK via z. LDS 96KB (1 block/CU).
// A 256-row block = two consecutive 128-row packed tiles; read swizzle qs invariant.
// Counted-vmcnt pipeline: stage=12 loads; vmcnt(12) retires only the older tile.
// XCD map: XCD r_ owns 2x2 panel tile: rbA=(r_&1)*2+(s&1), rbB=(r_>>1)*2+(s>>1).
__global__ __launch_bounds__(256, 1) void gemm_pk2(
    const unsigned short* __restrict__ Ah, const unsigned short* __restrict__ Al,
    const unsigned short* __restrict__ Bh, const unsigned short* __restrict__ Bl,
    float* __restrict__ T, int nKB, int stepsPerZ) {
  __shared__ __align__(16) unsigned short lds[2][6][4096];  // [buf][Ah0,Ah1,Al0,Al1,Bh,Bl]
  const int tid = threadIdx.x;
  const int w = tid >> 6, l = tid & 63;
  const int r_ = blockIdx.x, s_ = blockIdx.y;        // XCD residue, slot-within-XCD
  const int rbA = (r_ & 1) * 2 + (s_ & 1);           // 0..3 (256-row blocks)
  const int rbB = (r_ >> 1) * 2 + (s_ >> 1);         // 0..7 (128-col blocks)
  const int tk0 = blockIdx.z * stepsPerZ;
  const int fr = l & 15, q = l >> 4;
  const int wt = w >> 1;                             // A sub-tile (0/1): rows wt*128..
  const int wc = (w & 1) * 64;
  const int qs = q ^ (fr & 3) ^ (fr >> 2);           // per-lane-constant read swizzle
  const int aoff = (fr * 4 + qs) * 16;               // byte offset in 8KB tile; +m*1024
  const int boff = ((wc + fr) * 4 + qs) * 16;

  auto stage = [&](int bf, int tk) {                 // exactly 12 gload16 per thread
    const unsigned short* srcs[6] = {
        Ah + ((size_t)((rbA * 2)     * nKB + tk)) * 4096,
        Ah + ((size_t)((rbA * 2 + 1) * nKB + tk)) * 4096,
        Al + ((size_t)((rbA * 2)     * nKB + tk)) * 4096,
        Al + ((size_t)((rbA * 2 + 1) * nKB + tk)) * 4096,
        Bh + ((size_t)(rbB * nKB + tk)) * 4096,
        Bl + ((size_t)(rbB * nKB + tk)) * 4096};
#pragma unroll
    for (int t6 = 0; t6 < 6; ++t6)
#pragma unroll
      for (int rseg = 0; rseg < 2; ++rseg) {
        const int chunk = rseg * 256 + tid;
        gload16(srcs[t6] + (size_t)chunk * 8, &lds[bf][t6][(size_t)chunk * 8]);
      }
  };

  f32x4 acc[8][4];
#pragma unroll
  for (int m = 0; m < 8; ++m)
#pragma unroll
    for (int n = 0; n < 4; ++n) acc[m][n] = (f32x4){0.f, 0.f, 0.f, 0.f};

  // prologue: stage both buffers; wait only buf0's 12 (the oldest)
  stage(0, tk0);
  if (stepsPerZ > 1) {
    stage(1, tk0 + 1);
    asm volatile("s_waitcnt vmcnt(12)");
  } else {
    asm volatile("s_waitcnt vmcnt(0)");
  }
  __builtin_amdgcn_s_barrier();
  __builtin_amdgcn_sched_barrier(0);

  int cur = 0;
  for (int s = 0; s < stepsPerZ; ++s) {
    const char* LaH = (const char*)&lds[cur][wt][0];      // this wave's A-h tile
    const char* LaL = (const char*)&lds[cur][2 + wt][0];  // A-l tile
    const char* Lbh = (const char*)&lds[cur][4][0];
    const char* Lbl = (const char*)&lds[cur][5][0];
    bf16x8 bh[4], bl[4];
#pragma unroll
    for (int n = 0; n < 4; ++n) {
      bh[n] = *(const bf16x8*)(Lbh + boff + n * 1024);
      bl[n] = *(const bf16x8*)(Lbl + boff + n * 1024);
    }
#pragma unroll
    for (int m = 0; m < 8; ++m) {
      bf16x8 ahm = *(const bf16x8*)(LaH + aoff + m * 1024);
      bf16x8 alm = *(const bf16x8*)(LaL + aoff + m * 1024);
#pragma unroll
      for (int n = 0; n < 4; ++n) {
        acc[m][n] = __builtin_amdgcn_mfma_f32_16x16x32_bf16(ahm, bh[n], acc[m][n], 0, 0, 0);
        acc[m][n] = __builtin_amdgcn_mfma_f32_16x16x32_bf16(ahm, bl[n], acc[m][n], 0, 0, 0);
        acc[m][n] = __builtin_amdgcn_mfma_f32_16x16x32_bf16(alm, bh[n], acc[m][n], 0, 0, 0);
      }
    }
    if (s + 1 < stepsPerZ) {
      __builtin_amdgcn_s_barrier();                  // (A) all waves done reading buf[cur]
      if (s + 2 < stepsPerZ) {
        stage(cur, tk0 + s + 2);                     // overwrite cur; 12 new loads flying
        asm volatile("s_waitcnt vmcnt(12)");         // retire tile t+1 (older 12)
      } else {
        asm volatile("s_waitcnt vmcnt(0)");          // tail: retire t+1 fully
      }
      __builtin_amdgcn_s_barrier();                  // (B) buf[cur^1] ready block-wide
      __builtin_amdgcn_sched_barrier(0);             // pin next ds_reads behind (B)
    }
    cur ^= 1;
  }
  // epilogue: D row = (l>>4)*4 + j, col = l&15
  float* Tz = T + (size_t)blockIdx.z * (NROWS * REP);
#pragma unroll
  for (int m = 0; m < 8; ++m) {
    const int r0 = rbA * 256 + wt * 128 + m * 16 + ((l >> 4) << 2);
#pragma unroll
    for (int n = 0; n < 4; ++n) {
      const int c = rbB * 128 + wc + n * 16 + fr;
#pragma unroll
      for (int j = 0; j < 4; ++j) Tz[(size_t)(r0 + j) * REP + c] = acc[m][n][j];
    }
  }
}

// H1 = relu(sum_z T[z] + bias), written DIRECTLY as packed bf16 hi/lo tiles
__global__ __launch_bounds__(256) void combine8_relu_pack(
    const float* __restrict__ T, const float* __restrict__ bias,
    unsigned short* __restrict__ Oh, unsigned short* __restrict__ Ol) {
  const int e = (blockIdx.x * 256 + threadIdx.x) * 8;   // element idx in [1024x1024]
  const int MN = NROWS * REP;
  float s[8];
  {
    float4 a0 = *(const float4*)&T[e];
    float4 a1 = *(const float4*)&T[e + 4];
    s[0] = a0.x; s[1] = a0.y; s[2] = a0.z; s[3] = a0.w;
    s[4] = a1.x; s[5] = a1.y; s[6] = a1.z; s[7] = a1.w;
  }
#pragma unroll
  for (int z = 1; z < 8; ++z) {
    float4 a0 = *(const float4*)&T[z * MN + e];
    float4 a1 = *(const float4*)&T[z * MN + e + 4];
    s[0] += a0.x; s[1] += a0.y; s[2] += a0.z; s[3] += a0.w;
    s[4] += a1.x; s[5] += a1.y; s[6] += a1.z; s[7] += a1.w;
  }
  const int c0 = e & 1023;
  float4 b0 = *(const float4*)&bias[c0];
  float4 b1 = *(const float4*)&bias[c0 + 4];
  s[0] = fmaxf(s[0] + b0.x, 0.f); s[1] = fmaxf(s[1] + b0.y, 0.f);
  s[2] = fmaxf(s[2] + b0.z, 0.f); s[3] = fmaxf(s[3] + b0.w, 0.f);
  s[4] = fmaxf(s[4] + b1.x, 0.f); s[5] = fmaxf(s[5] + b1.y, 0.f);
  s[6] = fmaxf(s[6] + b1.z, 0.f); s[7] = fmaxf(s[7] + b1.w, 0.f);
  unsigned short hh[8], ll[8];
#pragma unroll
  for (int j = 0; j < 8; ++j) {
    hh[j] = rne_bf16(s[j]);
    ll[j] = rne_bf16(s[j] - bf16f(hh[j]));
  }
  const int r = e >> 10;
  const int kb = c0 >> 5, slot = (c0 >> 3) & 3;
  const int rb = r >> 7, rr = r & 127;
  size_t chunk = ((size_t)(rb * 32 + kb)) * 512 + rr * 4 + swz(rr, slot);
  unsigned short* dh = Oh + chunk * 8;
  unsigned short* dl = Ol + chunk * 8;
  *(ushort4*)dh = make_ushort4(hh[0], hh[1], hh[2], hh[3]);
  *(ushort4*)(dh + 4) = make_ushort4(hh[4], hh[5], hh[6], hh[7]);
  *(ushort4*)dl = make_ushort4(ll[0], ll[1], ll[2], ll[3]);
  *(ushort4*)(dl + 4) = make_ushort4(ll[4], ll[5], ll[6], ll[7]);
}

// H = relu(sum_{z<nz} T[z] + bias)  (fp32 out, runtime nz)
__global__ __launch_bounds__(256) void combineN_relu(
    const float* __restrict__ T, const float* __restrict__ bias,
    float* __restrict__ H, int nz) {
  const int i = blockIdx.x * 256 + threadIdx.x;
  const int MN4 = NROWS * REP / 4;
  const float4* t = (const float4*)T;
  float4 s0 = t[i];
  for (int z = 1; z < nz; ++z) {
    float4 v = t[i + z * MN4];
    s0.x += v.x; s0.y += v.y; s0.z += v.z; s0.w += v.w;
  }
  float4 bs = ((const float4*)bias)[i & 255];
  float4 r;
  r.x = fmaxf(s0.x + bs.x, 0.f);
  r.y = fmaxf(s0.y + bs.y, 0.f);
  r.z = fmaxf(s0.z + bs.z, 0.f);
  r.w = fmaxf(s0.w + bs.w, 0.f);
  ((float4*)H)[i] = r;
}

// ---------- mid-path GEMM (round-5 verified): A fp32 converted in-kernel, B packed ----------
__global__ __launch_bounds__(256) void gemm_pk(
    const float* __restrict__ A, const unsigned short* __restrict__ Bh,
    const unsigned short* __restrict__ Bl, float* __restrict__ T,
    int K, int nKB, int stepsPerZ) {
  __shared__ __align__(16) unsigned short lds[2][4][4096];
  const int tid = threadIdx.x;
  const int w = tid >> 6, l = tid & 63;
  const int bm = blockIdx.x * 128;
  const int bnb = blockIdx.y;
  const int tk0 = blockIdx.z * stepsPerZ;
  const int arow = tid >> 1, ahalf = tid & 1;
  const int fr = l & 15, q = l >> 4;
  const int wr = (w >> 1) * 64, wc = (w & 1) * 64;
  const int qs = q ^ (fr & 3) ^ (fr >> 2);
  const int aoff = ((wr + fr) * 4 + qs) * 16;
  const int boff = ((wc + fr) * 4 + qs) * 16;
  const float* aptr = A + (size_t)(bm + arow) * K + ahalf * 16;

  float4 av[4];
  auto loadA = [&](int tk) {
    const float* p = aptr + tk * 32;
#pragma unroll
    for (int j = 0; j < 4; ++j) av[j] = *(const float4*)(p + j * 4);
  };
  auto stageB = [&](int bf, int tk) {
    const unsigned short* gh = Bh + ((size_t)(bnb * nKB + tk)) * 4096;
    const unsigned short* gl_ = Bl + ((size_t)(bnb * nKB + tk)) * 4096;
#pragma unroll
    for (int rseg = 0; rseg < 2; ++rseg) {
      const int seg = rseg * 4 + w;
      gload16(gh + (size_t)(seg * 64 + l) * 8, &lds[bf][2][seg * 512]);
      gload16(gl_ + (size_t)(seg * 64 + l) * 8, &lds[bf][3][seg * 512]);
    }
  };
  auto writeA = [&](int bf) {
#pragma unroll
    for (int j = 0; j < 2; ++j) {
      const int s_ = ahalf * 2 + j;
      float fv[8] = {av[j * 2].x, av[j * 2].y, av[j * 2].z, av[j * 2].w,
                     av[j * 2 + 1].x, av[j * 2 + 1].y, av[j * 2 + 1].z, av[j * 2 + 1].w};
      unsigned hp[4], lp[4];
#pragma unroll
      for (int p2 = 0; p2 < 4; ++p2) {
        unsigned short h0 = rne_bf16(fv[2 * p2]), h1 = rne_bf16(fv[2 * p2 + 1]);
        float l0 = fv[2 * p2] - bf16f(h0), l1 = fv[2 * p2 + 1] - bf16f(h1);
        hp[p2] = (unsigned)h0 | ((unsigned)h1 << 16);
        lp[p2] = (unsigned)rne_bf16(l0) | ((unsigned)rne_bf16(l1) << 16);
      }
      const int chunk = arow * 4 + swz(arow, s_);
      *(uint4*)&lds[bf][0][chunk * 8] = make_uint4(hp[0], hp[1], hp[2], hp[3]);
      *(uint4*)&lds[bf][1][chunk * 8] = make_uint4(lp[0], lp[1], lp[2], lp[3]);
    }
  };

  f32x4 acc[4][4];
#pragma unroll
  for (int m = 0; m < 4; ++m)
#pragma unroll
    for (int n = 0; n < 4; ++n) acc[m][n] = (f32x4){0.f, 0.f, 0.f, 0.f};

  loadA(tk0);
  stageB(0, tk0);
  writeA(0);
  __syncthreads();
  int cur = 0;
  for (int s = 0; s < stepsPerZ; ++s) {
    const bool nx = (s + 1 < stepsPerZ);
    if (nx) { loadA(tk0 + s + 1); stageB(cur ^ 1, tk0 + s + 1); }
    const char* La = (const char*)&lds[cur][0][0];
    const char* Ll = (const char*)&lds[cur][1][0];
    const char* Lbh = (const char*)&lds[cur][2][0];
    const char* Lbl = (const char*)&lds[cur][3][0];
    bf16x8 ah[4], al[4], bh[4], bl[4];
#pragma unroll
    for (int m = 0; m < 4; ++m) {
      ah[m] = *(const bf16x8*)(La + aoff + m * 1024);
      al[m] = *(const bf16x8*)(Ll + aoff + m * 1024);
    }
#pragma unroll
    for (int n = 0; n < 4; ++n) {
      bh[n] = *(const bf16x8*)(Lbh + boff + n * 1024);
      bl[n] = *(const bf16x8*)(Lbl + boff + n * 1024);
    }
#pragma unroll
    for (int m = 0; m < 4; ++m)
#pragma unroll
      for (int n = 0; n < 4; ++n) {
        acc[m][n] = __builtin_amdgcn_mfma_f32_16x16x32_bf16(ah[m], bh[n], acc[m][n], 0, 0, 0);
        acc[m][n] = __builtin_amdgcn_mfma_f32_16x16x32_bf16(ah[m], bl[n], acc[m][n], 0, 0, 0);
        acc[m][n] = __builtin_amdgcn_mfma_f32_16x16x32_bf16(al[m], bh[n], acc[m][n], 0, 0, 0);
      }
    if (nx) writeA(cur ^ 1);
    __syncthreads();
    cur ^= 1;
  }
  float* Tz = T + (size_t)blockIdx.z * (NROWS * REP);
#pragma unroll
  for (int m = 0; m < 4; ++m) {
    const int r0 = bm + wr + m * 16 + ((l >> 4) << 2);
#pragma unroll
    for (int n = 0; n < 4; ++n) {
      const int c = bnb * 128 + wc + n * 16 + fr;
#pragma unroll
      for (int j = 0; j < 4; ++j) Tz[(size_t)(r0 + j) * REP + c] = acc[m][n][j];
    }
  }
}

// ---------------- legacy fp32 GEMM (fallback when ws is small) ----------------
__global__ __launch_bounds__(256) void gemm64(
    const float* __restrict__ A, const float* __restrict__ W,
    float* __restrict__ T, int K, int N, int kChunk) {
  __shared__ float As[32][68];
  __shared__ float Bs[32][64];
  const int tid = threadIdx.x;
  const int bm = blockIdx.x * 64, bn = blockIdx.y * 64;
  const int k0 = blockIdx.z * kChunk;
  const int tx = tid & 15, ty = tid >> 4;
  const int ar = tid >> 3;
  const int ac = (tid & 7) << 2;
  const int br = tid >> 4;
  const int bc = (tid & 15) << 2;
  float acc[4][4] = {{0.f,0.f,0.f,0.f},{0.f,0.f,0.f,0.f},{0.f,0.f,0.f,0.f},{0.f,0.f,0.f,0.f}};
  for (int kk = k0; kk < k0 + kChunk; kk += 32) {
    float4 a0 = *(const float4*)&A[(size_t)(bm + ar) * K + kk + ac];
    float4 a1 = *(const float4*)&A[(size_t)(bm + ar + 32) * K + kk + ac];
    float4 b0 = *(const float4*)&W[(size_t)(kk + br) * N + bn + bc];
    float4 b1 = *(const float4*)&W[(size_t)(kk + br + 16) * N + bn + bc];
    As[ac+0][ar] = a0.x; As[ac+1][ar] = a0.y; As[ac+2][ar] = a0.z; As[ac+3][ar] = a0.w;
    As[ac+0][ar+32] = a1.x; As[ac+1][ar+32] = a1.y; As[ac+2][ar+32] = a1.z; As[ac+3][ar+32] = a1.w;
    *(float4*)&Bs[br][bc]    = b0;
    *(float4*)&Bs[br+16][bc] = b1;
    __syncthreads();
#pragma unroll
    for (int k = 0; k < 32; ++k) {
      float4 av = *(const float4*)&As[k][ty << 2];
      float4 bv = *(const float4*)&Bs[k][tx << 2];
      float a_[4] = {av.x, av.y, av.z, av.w};
      float b_[4] = {bv.x, bv.y, bv.z, bv.w};
#pragma unroll
      for (int i = 0; i < 4; ++i)
#pragma unroll
        for (int j = 0; j < 4; ++j)
          acc[i][j] = fmaf(a_[i], b_[j], acc[i][j]);
    }
    __syncthreads();
  }
  float* Tz = T + (size_t)blockIdx.z * NROWS * REP;
#pragma unroll
  for (int i = 0; i < 4; ++i) {
    float4 v = make_float4(acc[i][0], acc[i][1], acc[i][2], acc[i][3]);
    *(float4*)&Tz[(size_t)(bm + (ty << 2) + i) * N + bn + (tx << 2)] = v;
  }
}

// ---------- fused heads: wave-per-row, coalesced Wt reads, shfl reduce, softmax+decode ----------
__global__ __launch_bounds__(256) void heads2(
    const float* __restrict__ H2, const float* __restrict__ Wt,
    const float* __restrict__ bcv, const float* __restrict__ bbv,
    const float* __restrict__ props, float* __restrict__ pb, float* __restrict__ sc) {
  const int wave = threadIdx.x >> 6, l = threadIdx.x & 63;
  const int n = blockIdx.x * 4 + wave;
  const float* h = H2 + (size_t)n * REP + l * 16;
  float4 h0 = *(const float4*)h, h1 = *(const float4*)(h + 4);
  float4 h2v = *(const float4*)(h + 8), h3 = *(const float4*)(h + 12);
  float outv[25];
#pragma unroll
  for (int o = 0; o < 25; ++o) {
    const float* wp = Wt + o * REP + l * 16;
    float4 w0 = *(const float4*)wp, w1 = *(const float4*)(wp + 4);
    float4 w2 = *(const float4*)(wp + 8), w3 = *(const float4*)(wp + 12);
    float d = h0.x * w0.x;
    d = fmaf(h0.y, w0.y, d); d = fmaf(h0.z, w0.z, d); d = fmaf(h0.w, w0.w, d);
    d = fmaf(h1.x, w1.x, d); d = fmaf(h1.y, w1.y, d); d = fmaf(h1.z, w1.z, d); d = fmaf(h1.w, w1.w, d);
    d = fmaf(h2v.x, w2.x, d); d = fmaf(h2v.y, w2.y, d); d = fmaf(h2v.z, w2.z, d); d = fmaf(h2v.w, w2.w, d);
    d = fmaf(h3.x, w3.x, d); d = fmaf(h3.y, w3.y, d); d = fmaf(h3.z, w3.z, d); d = fmaf(h3.w, w3.w, d);
#pragma unroll
    for (int m = 1; m < 64; m <<= 1) d += __shfl_xor(d, m);
    outv[o] = d + ((o < 5) ? bcv[o] : bbv[o - 5]);
  }
  const float mx = fmaxf(fmaxf(fmaxf(outv[0], outv[1]), fmaxf(outv[2], outv[3])), outv[4]);
  const float e0 = expf(outv[0] - mx), e1 = expf(outv[1] - mx), e2 = expf(outv[2] - mx);
  const float e3 = expf(outv[3] - mx), e4 = expf(outv[4] - mx);
  const float inv = 1.0f / (e0 + e1 + e2 + e3 + e4);
  const float s1 = e1 * inv, s2 = e2 * inv, s3 = e3 * inv, s4 = e4 * inv;
  const float* pr = props + (size_t)n * 4;
  const float x1 = pr[0], y1 = pr[1], x2 = pr[2], y2 = pr[3];
  const float bw = x2 - x1, bh = y2 - y1;
  const float cx = x1 + 0.5f * bw, cy = y1 + 0.5f * bh;
  const int img = n >> 9, pbase = (n & 511) << 2;
#pragma unroll
  for (int c = 1; c <= 4; ++c) {
    if (l == c - 1) {
      const float r0 = outv[5 + c * 4 + 0], r1 = outv[5 + c * 4 + 1];
      const float r2 = outv[5 + c * 4 + 2], r3 = outv[5 + c * 4 + 3];
      const float dx = r0 / 10.0f, dy = r1 / 10.0f;
      const float dw = fminf(r2 / 5.0f, BBOX_CLIP_F);
      const float dh = fminf(r3 / 5.0f, BBOX_CLIP_F);
      const float pcx = dx * bw + cx, pcy = dy * bh + cy;
      const float pw = expf(dw) * bw, ph = expf(dh) * bh;
      float bx1 = pcx - 0.5f * pw, by1 = pcy - 0.5f * ph;
      float bx2 = pcx + 0.5f * pw, by2 = pcy + 0.5f * ph;
      bx1 = fminf(fmaxf(bx1, 0.f), 800.f);
      by1 = fminf(fmaxf(by1, 0.f), 800.f);
      bx2 = fminf(fmaxf(bx2, 0.f), 800.f);
      by2 = fminf(fmaxf(by2, 0.f), 800.f);
      const int pidx = pbase + (c - 1);
      float* o = pb + (size_t)(img * NDET + pidx) * 4;
      o[0] = bx1; o[1] = by1; o[2] = bx2; o[3] = by2;
      const float smc = (c == 1) ? s1 : (c == 2) ? s2 : (c == 3) ? s3 : s4;
      sc[img * NDET + pidx] = smc;
    }
  }
}

// Per proposal row (fallback paths): 25 head outputs, softmax, decode+clip
__global__ __launch_bounds__(256) void heads_kernel(
    const float* __restrict__ H2, const float* __restrict__ Wc, const float* __restrict__ bcv,
    const float* __restrict__ Wb, const float* __restrict__ bbv,
    const float* __restrict__ props, float* __restrict__ pb, float* __restrict__ sc) {
  const int n = blockIdx.x;
  __shared__ float hrow[REP];
  __shared__ float part[25][8];
  __shared__ float outv[25];
  __shared__ float smax[5];
  const int tid = threadIdx.x;
  ((float4*)hrow)[tid] = ((const float4*)(H2 + (size_t)n * REP))[tid];
  __syncthreads();
  if (tid < 200) {
    const int o = tid >> 3, s = tid & 7;
    float a = 0.f;
    if (o < 5) {
      const float* w = Wc + o;
      for (int k = s * 128; k < s * 128 + 128; ++k) a = fmaf(hrow[k], w[(size_t)k * 5], a);
    } else {
      const float* w = Wb + (o - 5);
      for (int k = s * 128; k < s * 128 + 128; ++k) a = fmaf(hrow[k], w[(size_t)k * 20], a);
    }
    part[o][s] = a;
  }
  __syncthreads();
  if (tid < 25) {
    float a = ((part[tid][0] + part[tid][1]) + (part[tid][2] + part[tid][3]))
            + ((part[tid][4] + part[tid][5]) + (part[tid][6] + part[tid][7]));
    a += (tid < 5) ? bcv[tid] : bbv[tid - 5];
    outv[tid] = a;
  }
  __syncthreads();
  if (tid == 0) {
    float m = outv[0];
    for (int c = 1; c < 5; ++c) m = fmaxf(m, outv[c]);
    float e[5], ssum = 0.f;
    for (int c = 0; c < 5; ++c) { e[c] = expf(outv[c] - m); ssum += e[c]; }
    for (int c = 0; c < 5; ++c) smax[c] = e[c] / ssum;
  }
  __syncthreads();
  if (tid < 4) {
    const int c = tid + 1;
    const float* pr = props + (size_t)n * 4;
    const float x1 = pr[0], y1 = pr[1], x2 = pr[2], y2 = pr[3];
    const float w = x2 - x1, h = y2 - y1;
    const float cx = x1 + 0.5f * w, cy = y1 + 0.5f * h;
    const float r0 = outv[5 + c * 4 + 0], r1 = outv[5 + c * 4 + 1];
    const float r2 = outv[5 + c * 4 + 2], r3 = outv[5 + c * 4 + 3];
    const float dx = r0 / 10.0f, dy = r1 / 10.0f;
    const float dw = fminf(r2 / 5.0f, BBOX_CLIP_F);
    const float dh = fminf(r3 / 5.0f, BBOX_CLIP_F);
    const float pcx = dx * w + cx, pcy = dy * h + cy;
    const float pw = expf(dw) * w, ph = expf(dh) * h;
    float bx1 = pcx - 0.5f * pw, by1 = pcy - 0.5f * ph;
    float bx2 = pcx + 0.5f * pw, by2 = pcy + 0.5f * ph;
    bx1 = fminf(fmaxf(bx1, 0.f), 800.f);
    by1 = fminf(fmaxf(by1, 0.f), 800.f);
    bx2 = fminf(fmaxf(bx2, 0.f), 800.f);
    by2 = fminf(fmaxf(by2, 0.f), 800.f);
    const int img = n >> 9;
    const int pidx = ((n & 511) << 2) + (c - 1);
    float* o = pb + (size_t)(img * NDET + pidx) * 4;
    o[0] = bx1; o[1] = by1; o[2] = bx2; o[3] = by2;
    sc[img * NDET + pidx] = smax[c];
  }
}

// ---------- fused: stable descending bitonic sort + prep (gather, valid bits, offsets) ----------
__global__ __launch_bounds__(1024) void sortprep_kernel(
    const float* __restrict__ sc, const float* __restrict__ pb,
    float* __restrict__ sbox, float* __restrict__ soff, float* __restrict__ sscore,
    float* __restrict__ sarea, float* __restrict__ slab, unsigned* __restrict__ vword) {
  const int b = blockIdx.x;
  __shared__ unsigned long long key[NDET];
  const int tid = threadIdx.x;
  for (int t = tid; t < NDET; t += 1024) {
    unsigned bits = __float_as_uint(sc[b * NDET + t]);   // scores > 0 -> monotonic
    key[t] = ((unsigned long long)bits << 32) | (unsigned)(~t);
  }
  __syncthreads();
  for (int k = 2; k <= NDET; k <<= 1) {
    for (int j = k >> 1; j > 0; j >>= 1) {
      for (int t = tid; t < NDET; t += 1024) {
        const int ixj = t ^ j;
        if (ixj > t) {
          const bool up = (t & k) == 0;
          unsigned long long a = key[t], bb_ = key[ixj];
          if ((a < bb_) == up) { key[t] = bb_; key[ixj] = a; }
        }
      }
      __syncthreads();
    }
  }
  for (int pass = 0; pass < 2; ++pass) {
    const int i = pass * 1024 + tid;
    const unsigned oi = ~(unsigned)key[i];
    const float* bx = pb + (size_t)(b * NDET + oi) * 4;
    const float x1 = bx[0], y1 = bx[1], x2 = bx[2], y2 = bx[3];
    const float s = sc[b * NDET + oi];
    const float lab = (float)((oi & 3) + 1);
    const bool valid = (s > 0.05f) && ((x2 - x1) >= 0.01f) && ((y2 - y1) >= 0.01f);
    const float off = lab * 801.0f;
    float* sb = sbox + (size_t)(b * NDET + i) * 4;
    sb[0] = x1; sb[1] = y1; sb[2] = x2; sb[3] = y2;
    float* so = soff + (size_t)(b * NDET + i) * 4;
    so[0] = x1 + off; so[1] = y1 + off; so[2] = x2 + off; so[3] = y2 + off;
    sscore[b * NDET + i] = s;
    sarea[b * NDET + i] = (x2 - x1) * (y2 - y1);
    slab[b * NDET + i] = lab;
    const unsigned long long bal = __ballot(valid);
    if ((i & 31) == 0) vword[b * 64 + (i >> 5)] = (unsigned)(bal >> (i & 32));
  }
}

// Suppression bitmask, CONTIGUOUS layout: word w of row i covers rows [w*32, w*32+32)
__global__ __launch_bounds__(256) void mask_kernel(
    const float* __restrict__ soff, const float* __restrict__ sarea,
    unsigned* __restrict__ mask) {
  const int b = blockIdx.y;
  __shared__ float xx1[NDET + 64], yy1[NDET + 64], xx2[NDET + 64], yy2[NDET + 64];
  __shared__ float ar[NDET + 64];
  const int tid = threadIdx.x;
  for (int t = tid; t < NDET; t += 256) {
    float4 v = *(const float4*)(soff + ((size_t)b * NDET + t) * 4);
    const int pt = t + (t >> 5);
    xx1[pt] = v.x; yy1[pt] = v.y; xx2[pt] = v.z; yy2[pt] = v.w;
    ar[pt] = sarea[b * NDET + t];
  }
  __syncthreads();
  const int li = tid >> 6;
  const int w  = tid & 63;
#pragma unroll
  for (int pass = 0; pass < 4; ++pass) {
    const int i = blockIdx.x * 16 + pass * 4 + li;
    const int pi = i + (i >> 5);
    const float ax1 = xx1[pi], ay1 = yy1[pi], ax2 = xx2[pi], ay2 = yy2[pi];
    const float aa = ar[pi];
    unsigned bits = 0;
#pragma unroll 4
    for (int bb = 0; bb < 32; ++bb) {
      const int j = w * 32 + bb;
      const int pj = w * 33 + bb;
      const float ix = fmaxf(fminf(ax2, xx2[pj]) - fmaxf(ax1, xx1[pj]), 0.f);
      const float iy = fmaxf(fminf(ay2, yy2[pj]) - fmaxf(ay1, yy1[pj]), 0.f);
      const float inter = ix * iy;
      const float iou = inter / (aa + ar[pj] - inter + 1e-9f);
      if (j > i && iou > 0.5f) bits |= (1u << bb);
    }
    mask[((size_t)b * NDET + i) * 64 + w] = bits;
  }
}

// Greedy NMS scan: suppression word in REGISTER per lane; shfl (no LDS/barrier) per keep.
__global__ __launch_bounds__(64) void scan_kernel(
    const unsigned* __restrict__ vword, const unsigned* __restrict__ mask,
    const float* __restrict__ sbox, const float* __restrict__ sscore,
    const float* __restrict__ slab, float* __restrict__ out) {
  const int b = blockIdx.x;
  const int lane = threadIdx.x;
  unsigned supreg = ~vword[b * 64 + lane];   // invalid rows pre-suppressed
  __shared__ unsigned short klist[DETS];
  int kcnt = 0;
  for (int w = 0; w < 64 && kcnt < DETS; ++w) {
    unsigned avail = ~__shfl(supreg, w);
    while (avail) {
      const int bb = __ffs(avail) - 1;
      const int i = w * 32 + bb;
      if (lane == 0) klist[kcnt] = (unsigned short)i;
      kcnt++;
      if (kcnt == DETS) break;
      supreg |= mask[((size_t)b * NDET + i) * 64 + lane];
      avail = ~__shfl(supreg, w) & (0xFFFFFFFEu << bb);
    }
  }
  __syncthreads();
  for (int s = lane; s < DETS; s += 64) {
    float b0 = 0.f, b1 = 0.f, b2 = 0.f, b3 = 0.f, sv = 0.f, lv = 0.f;
    if (s < kcnt) {
      const int i = klist[s];
      const float* bx = sbox + ((size_t)b * NDET + i) * 4;
      b0 = bx[0]; b1 = bx[1]; b2 = bx[2]; b3 = bx[3];
      sv = sscore[b * NDET + i];
      lv = slab[b * NDET + i];
    }
    float* ob = out + ((size_t)b * DETS + s) * 4;
    ob[0] = b0; ob[1] = b1; ob[2] = b2; ob[3] = b3;
    out[2 * DETS * 4 + b * DETS + s] = sv;
    out[2 * DETS * 4 + 2 * DETS + b * DETS + s] = lv;
  }
}

extern "C" void kernel_launch(void* const* d_in, const int* in_sizes, int n_in,
                              void* d_out, int out_size, void* d_ws, size_t ws_size,
                              hipStream_t stream) {
  const float* X     = (const float*)d_in[0];
  const float* props = (const float*)d_in[1];
  const float* W1    = (const float*)d_in[2];
  const float* b1    = (const float*)d_in[3];
  const float* W2    = (const float*)d_in[4];
  const float* b2    = (const float*)d_in[5];
  const float* Wc    = (const float*)d_in[6];
  const float* bc    = (const float*)d_in[7];
  const float* Wb    = (const float*)d_in[8];
  const float* bb    = (const float*)d_in[9];
  float* out = (float*)d_out;

  const size_t POST_B = 3200000;
  const size_t NEED_BIG =
      (size_t)9 * 1048576 * 4 +
      (size_t)4 * (size_t)K1 * 1024 * 2 +
      (size_t)4 * 1048576 * 2 + POST_B;
  const size_t NEED_MID =
      (size_t)10 * 1048576 * 4 +
      (size_t)2 * (size_t)K1 * 1024 * 2 +
      (size_t)2 * 1048576 * 2 + 2500000;

  float *T, *H1 = nullptr, *H2, *pb, *sc, *Wt = nullptr;
  unsigned short *W1h = nullptr, *W1l = nullptr, *W2h = nullptr, *W2l = nullptr;
  unsigned short *Ahp = nullptr, *Alp = nullptr, *H1h = nullptr, *H1l = nullptr;
  const int path = (ws_size >= NEED_BIG) ? 2 : (ws_size >= NEED_MID) ? 1 : 0;
  if (path == 2) {
    T   = (float*)d_ws;                  // 8 * 1048576
    H2  = T + 8 * 1048576;
    W1h = (unsigned short*)(H2 + 1048576);
    W1l = W1h + (size_t)K1 * 1024;
    W2h = W1l + (size_t)K1 * 1024;
    W2l = W2h + 1048576;
    Ahp = W2l + 1048576;
    Alp = Ahp + (size_t)K1 * 1024;
    H1h = Alp + (size_t)K1 * 1024;
    H1l = H1h + 1048576;
    Wt  = (float*)(H1l + 1048576);       // 25*1024 floats
    pb  = Wt + 25 * 1024;
  } else if (path == 1) {
    T   = (float*)d_ws;
    H1  = T + 8 * 1048576;
    H2  = H1 + 1048576;
    W1h = (unsigned short*)(H2 + 1048576);
    W1l = W1h + (size_t)K1 * 1024;
    W2h = W1l + (size_t)K1 * 1024;
    W2l = W2h + 1048576;
    pb  = (float*)(W2l + 1048576);
  } else {
    T  = (float*)d_ws;
    H1 = T + 4 * 1048576;
    H2 = H1 + 1048576;
    pb = H2 + 1048576;
  }
  sc = pb + 2 * NDET * 4;
  unsigned* sidx = (unsigned*)(sc + 2 * NDET);   // kept for layout stability (unused)
  float* sbox   = (float*)(sidx + 2 * NDET);
  float* soff   = sbox + 2 * NDET * 4;
  float* sscore = soff + 2 * NDET * 4;
  float* sarea  = sscore + 2 * NDET;
  float* slab   = sarea + 2 * NDET;
  unsigned* vword = (unsigned*)(slab + 2 * NDET);
  unsigned* mask  = vword + 128;

  if (path == 2) {
    pack_fused<<<19940, 256, 0, stream>>>(X, W1, W2, Wc, Wb,
                                          Ahp, Alp, W1h, W1l, W2h, W2l, Wt);
    // GEMM1: 256x128 tiles, grid (8 XCD residues, 4 slots, 8 z) = 256 blocks (1/CU)
    gemm_pk2<<<dim3(8, 4, 8), 256, 0, stream>>>(Ahp, Alp, W1h, W1l, T, K1 / 32, 49);
    combine8_relu_pack<<<512, 256, 0, stream>>>(T, b1, H1h, H1l);
    // GEMM2: grid (8,4,4) = 128 blocks, 8 k-steps per z
    gemm_pk2<<<dim3(8, 4, 4), 256, 0, stream>>>(H1h, H1l, W2h, W2l, T, 32, 8);
    combineN_relu<<<1024, 256, 0, stream>>>(T, b2, H2, 4);
    heads2<<<256, 256, 0, stream>>>(H2, Wt, bc, bb, props, pb, sc);
  } else if (path == 1) {
    pack_b<<<dim3(K1 / 32, 32), 256, 0, stream>>>(W1, W1h, W1l, K1 / 32);
    pack_b<<<dim3(32, 32), 256, 0, stream>>>(W2, W2h, W2l, 32);
    gemm_pk<<<dim3(8, 8, 8), 256, 0, stream>>>(X, W1h, W1l, T, K1, K1 / 32, 49);
    combineN_relu<<<1024, 256, 0, stream>>>(T, b1, H1, 8);
    gemm_pk<<<dim3(8, 8, 4), 256, 0, stream>>>(H1, W2h, W2l, T, REP, 32, 8);
    combineN_relu<<<1024, 256, 0, stream>>>(T, b2, H2, 4);
    heads_kernel<<<1024, 256, 0, stream>>>(H2, Wc, bc, Wb, bb, props, pb, sc);
  } else {
    gemm64<<<dim3(16, 16, 4), 256, 0, stream>>>(X, W1, T, K1, REP, K1 / 4);
    combineN_relu<<<1024, 256, 0, stream>>>(T, b1, H1, 4);
    gemm64<<<dim3(16, 16, 4), 256, 0, stream>>>(H1, W2, T, REP, REP, REP / 4);
    combineN_relu<<<1024, 256, 0, stream>>>(T, b2, H2, 4);
    heads_kernel<<<1024, 256, 0, stream>>>(H2, Wc, bc, Wb, bb, props, pb, sc);
  }
  sortprep_kernel<<<2, 1024, 0, stream>>>(sc, pb, sbox, soff, sscore, sarea, slab, vword);
  mask_kernel<<<dim3(128, 2), 256, 0, stream>>>(soff, sarea, mask);
  scan_kernel<<<2, 64, 0, stream>>>(vword, mask, sbox, sscore, slab, out);
}

// Round 15
// 230.540 us; speedup vs baseline: 1.0255x; 1.0255x over previous
//
#include <hip/hip_runtime.h>
#include <math.h>

#define NROWS 1024      // B*P
#define K1    12544
#define REP   1024
#define NDET  2048      // P*(C-1)
#define DETS  100
#define BBOX_CLIP_F 4.135166556742356f

typedef __attribute__((ext_vector_type(8))) short bf16x8;
typedef __attribute__((ext_vector_type(4))) float f32x4;

__device__ __forceinline__ unsigned short rne_bf16(float x) {
  unsigned u = __float_as_uint(x);
  u += 0x7fffu + ((u >> 16) & 1u);
  return (unsigned short)(u >> 16);
}
__device__ __forceinline__ float bf16f(unsigned short h) {
  return __uint_as_float(((unsigned)h) << 16);
}
// chunk swizzle: slot s of row r lives at chunk r*4 + SWZ(r,s) within an 8KB tile
__device__ __forceinline__ int swz(int r, int s) {
  return s ^ (r & 3) ^ ((r >> 2) & 3);
}
__device__ __forceinline__ void gload16(const void* g, void* lds) {
  __builtin_amdgcn_global_load_lds(
      (const __attribute__((address_space(1))) unsigned int*)g,
      (__attribute__((address_space(3))) unsigned int*)lds, 16, 0, 0);
}

// ---------- fused pack: W1, W2 (transpose-pack), A (row-pack), Wt (25x1024) ----------
// grid = 12544 (W1) + 1024 (W2) + 6272 (A) + 100 (Wt) = 19940 blocks x 256
__global__ __launch_bounds__(256) void pack_fused(
    const float* __restrict__ X, const float* __restrict__ W1,
    const float* __restrict__ W2, const float* __restrict__ Wc,
    const float* __restrict__ Wb,
    unsigned short* __restrict__ Ahp, unsigned short* __restrict__ Alp,
    unsigned short* __restrict__ W1h, unsigned short* __restrict__ W1l,
    unsigned short* __restrict__ W2h, unsigned short* __restrict__ W2l,
    float* __restrict__ Wt) {
  __shared__ unsigned short th[32 * 36], tl[32 * 36];
  const int id = blockIdx.x;
  const int t = threadIdx.x;
  if (id < 13568) {
    // ---- pack_b for W1 (nKB=392) or W2 (nKB=32) ----
    const float* W;
    unsigned short *Oh, *Ol;
    int nKB, kb, n0;
    if (id < 12544) { W = W1; Oh = W1h; Ol = W1l; nKB = 392; kb = id % 392; n0 = (id / 392) * 32; }
    else { const int r2 = id - 12544; W = W2; Oh = W2h; Ol = W2l; nKB = 32; kb = r2 % 32; n0 = (r2 / 32) * 32; }
    const int r = t >> 3, c4 = (t & 7) << 2;          // r = k_local
    float4 v = *(const float4*)&W[(size_t)(kb * 32 + r) * REP + n0 + c4];
    float fv[4] = {v.x, v.y, v.z, v.w};
#pragma unroll
    for (int j = 0; j < 4; ++j) {
      unsigned short h = rne_bf16(fv[j]);
      th[(c4 + j) * 36 + r] = h;
      tl[(c4 + j) * 36 + r] = rne_bf16(fv[j] - bf16f(h));
    }
    __syncthreads();
    const int half = t >> 7;                           // 0 -> h, 1 -> l
    const int n_loc = (t & 127) >> 2, slot = t & 3;
    const unsigned short* src = (half ? tl : th) + n_loc * 36 + slot * 8;
    ushort4 u0 = *(const ushort4*)src;
    ushort4 u1 = *(const ushort4*)(src + 4);
    const int n = n0 + n_loc, rb = n >> 7, rr = n & 127;
    size_t chunk = ((size_t)(rb * nKB + kb)) * 512 + rr * 4 + swz(rr, slot);
    unsigned short* dst = (half ? Ol : Oh) + chunk * 8;
    *(ushort4*)dst = u0;
    *(ushort4*)(dst + 4) = u1;
  } else if (id < 19840) {
    // ---- pack_a for X (nKB=392) ----
    const int r_ = id - 13568;
    const int kb = r_ % 392;
    const int row = (r_ / 392) * 64 + (t >> 2);
    const int slot = t & 3;
    const float* p = X + (size_t)row * K1 + kb * 32 + slot * 8;
    float4 f0 = *(const float4*)p;
    float4 f1 = *(const float4*)(p + 4);
    float fv[8] = {f0.x, f0.y, f0.z, f0.w, f1.x, f1.y, f1.z, f1.w};
    unsigned short hh[8], ll[8];
#pragma unroll
    for (int j = 0; j < 8; ++j) {
      hh[j] = rne_bf16(fv[j]);
      ll[j] = rne_bf16(fv[j] - bf16f(hh[j]));
    }
    const int rb = row >> 7, rr = row & 127;
    size_t chunk = ((size_t)(rb * 392 + kb)) * 512 + rr * 4 + swz(rr, slot);
    unsigned short* dh = Ahp + chunk * 8;
    unsigned short* dl = Alp + chunk * 8;
    *(ushort4*)dh = make_ushort4(hh[0], hh[1], hh[2], hh[3]);
    *(ushort4*)(dh + 4) = make_ushort4(hh[4], hh[5], hh[6], hh[7]);
    *(ushort4*)dl = make_ushort4(ll[0], ll[1], ll[2], ll[3]);
    *(ushort4*)(dl + 4) = make_ushort4(ll[4], ll[5], ll[6], ll[7]);
  } else {
    // ---- pack_w25: Wt[25][1024] from Wc[1024][5], Wb[1024][20] ----
    const int i = (id - 19840) * 256 + t;
    if (i < 25 * 1024) {
      const int o = i >> 10, k = i & 1023;
      Wt[i] = (o < 5) ? Wc[(size_t)k * 5 + o] : Wb[(size_t)k * 20 + (o - 5)];
    }
  }
}

// ---------- standalone packs (fallback path 1) ----------
__global__ __launch_bounds__(256) void pack_b(
    const float* __restrict__ W, unsigned short* __restrict__ Oh,
    unsigned short* __restrict__ Ol, int nKB) {
  __shared__ unsigned short th[32 * 36], tl[32 * 36];
  const int kb = blockIdx.x, n0 = blockIdx.y * 32;
  const int t = threadIdx.x;
  const int r = t >> 3, c4 = (t & 7) << 2;
  float4 v = *(const float4*)&W[(size_t)(kb * 32 + r) * REP + n0 + c4];
  float fv[4] = {v.x, v.y, v.z, v.w};
#pragma unroll
  for (int j = 0; j < 4; ++j) {
    unsigned short h = rne_bf16(fv[j]);
    th[(c4 + j) * 36 + r] = h;
    tl[(c4 + j) * 36 + r] = rne_bf16(fv[j] - bf16f(h));
  }
  __syncthreads();
  const int half = t >> 7;
  const int n_loc = (t & 127) >> 2, slot = t & 3;
  const unsigned short* src = (half ? tl : th) + n_loc * 36 + slot * 8;
  ushort4 u0 = *(const ushort4*)src;
  ushort4 u1 = *(const ushort4*)(src + 4);
  const int n = n0 + n_loc, rb = n >> 7, rr = n & 127;
  size_t chunk = ((size_t)(rb * nKB + kb)) * 512 + rr * 4 + swz(rr, slot);
  unsigned short* dst = (half ? Ol : Oh) + chunk * 8;
  *(ushort4*)dst = u0;
  *(ushort4*)(dst + 4) = u1;
}

// ---------- MFMA GEMM, 128x128 tile (round-12 verified) + T5 setprio graft ----------
// 4 waves x (64x64 via 4x4 16x16x32 frags), BK=32, splitK via z.
// XCD tile-swizzle. Counted-vmcnt pipeline: stage(t+2) loads stay in flight
// across both barriers; vmcnt(8) retires only the older tile's 8 loads.
__global__ __launch_bounds__(256) void gemm_pk2(
    const unsigned short* __restrict__ Ah, const unsigned short* __restrict__ Al,
    const unsigned short* __restrict__ Bh, const unsigned short* __restrict__ Bl,
    float* __restrict__ T, int nKB, int stepsPerZ) {
  __shared__ __align__(16) unsigned short lds[2][4][4096];  // [buf][Ah,Al,Bh,Bl] 64KB
  const int tid = threadIdx.x;
  const int w = tid >> 6, l = tid & 63;
  const int r_ = blockIdx.x, t_ = blockIdx.y;        // XCD residue, slot-within-XCD
  const int rbA = (r_ & 3) * 2 + (t_ & 1);
  const int rbB = (r_ >> 2) * 4 + (t_ >> 1);
  const int tk0 = blockIdx.z * stepsPerZ;
  const int fr = l & 15, q = l >> 4;
  const int wr = (w >> 1) * 64, wc = (w & 1) * 64;
  const int qs = q ^ (fr & 3) ^ (fr >> 2);           // per-lane-constant read swizzle
  const int aoff = ((wr + fr) * 4 + qs) * 16;        // byte offset; +m*1024 per frag
  const int boff = ((wc + fr) * 4 + qs) * 16;

  auto stage = [&](int bf, int tk) {                 // exactly 8 gload16 per thread
    const unsigned short* ga_h = Ah + ((size_t)(rbA * nKB + tk)) * 4096;
    const unsigned short* ga_l = Al + ((size_t)(rbA * nKB + tk)) * 4096;
    const unsigned short* gb_h = Bh + ((size_t)(rbB * nKB + tk)) * 4096;
    const unsigned short* gb_l = Bl + ((size_t)(rbB * nKB + tk)) * 4096;
#pragma unroll
    for (int rseg = 0; rseg < 2; ++rseg) {
      const int seg = rseg * 4 + w;
      const size_t go = (size_t)(seg * 64 + l) * 8;
      gload16(ga_h + go, &lds[bf][0][seg * 512]);
      gload16(ga_l + go, &lds[bf][1][seg * 512]);
      gload16(gb_h + go, &lds[bf][2][seg * 512]);
      gload16(gb_l + go, &lds[bf][3][seg * 512]);
    }
  };

  f32x4 acc[4][4];
#pragma unroll
  for (int m = 0; m < 4; ++m)
#pragma unroll
    for (int n = 0; n < 4; ++n) acc[m][n] = (f32x4){0.f, 0.f, 0.f, 0.f};

  // prologue: stage both buffers; wait only buf0's 8 (the oldest)
  stage(0, tk0);
  if (stepsPerZ > 1) {
    stage(1, tk0 + 1);
    asm volatile("s_waitcnt vmcnt(8)");
  } else {
    asm volatile("s_waitcnt vmcnt(0)");
  }
  __builtin_amdgcn_s_barrier();
  __builtin_amdgcn_sched_barrier(0);

  int cur = 0;
  for (int s = 0; s < stepsPerZ; ++s) {
    const char* La  = (const char*)&lds[cur][0][0];
    const char* Ll  = (const char*)&lds[cur][1][0];
    const char* Lbh = (const char*)&lds[cur][2][0];
    const char* Lbl = (const char*)&lds[cur][3][0];
    bf16x8 ah[4], al[4], bh[4], bl[4];
#pragma unroll
    for (int m = 0; m < 4; ++m) {
      ah[m] = *(const bf16x8*)(La + aoff + m * 1024);
      al[m] = *(const bf16x8*)(Ll + aoff + m * 1024);
    }
#pragma unroll
    for (int n = 0; n < 4; ++n) {
      bh[n] = *(const bf16x8*)(Lbh + boff + n * 1024);
      bl[n] = *(const bf16x8*)(Lbl + boff + n * 1024);
    }
    __builtin_amdgcn_s_setprio(1);                   // T5: favor MFMA-issuing wave
#pragma unroll
    for (int m = 0; m < 4; ++m)
#pragma unroll
      for (int n = 0; n < 4; ++n) {
        acc[m][n] = __builtin_amdgcn_mfma_f32_16x16x32_bf16(ah[m], bh[n], acc[m][n], 0, 0, 0);
        acc[m][n] = __builtin_amdgcn_mfma_f32_16x16x32_bf16(ah[m], bl[n], acc[m][n], 0, 0, 0);
        acc[m][n] = __builtin_amdgcn_mfma_f32_16x16x32_bf16(al[m], bh[n], acc[m][n], 0, 0, 0);
      }
    __builtin_amdgcn_s_setprio(0);
    if (s + 1 < stepsPerZ) {
      __builtin_amdgcn_s_barrier();                  // (A) all waves done reading buf[cur]
      if (s + 2 < stepsPerZ) {
        stage(cur, tk0 + s + 2);                     // overwrite cur; 8 new loads flying
        asm volatile("s_waitcnt vmcnt(8)");          // retire tile t+1 (older 8)
      } else {
        asm volatile("s_waitcnt vmcnt(0)");          // tail: retire t+1 fully
      }
      __builtin_amdgcn_s_barrier();                  // (B) buf[cur^1] ready block-wide
      __builtin_amdgcn_sched_barrier(0);             // pin next ds_reads behind (B)
    }
    cur ^= 1;
  }
  // epilogue: D row = (l>>4)*4 + j, col = l&15
  float* Tz = T + (size_t)blockIdx.z * (NROWS * REP);
#pragma unroll
  for (int m = 0; m < 4; ++m) {
    const int r0 = rbA * 128 + wr + m * 16 + ((l >> 4) << 2);
#pragma unroll
    for (int n = 0; n < 4; ++n) {
      const int c = rbB * 128 + wc + n * 16 + fr;
#pragma unroll
      for (int j = 0; j < 4; ++j) Tz[(size_t)(r0 + j) * REP + c] = acc[m][n][j];
    }
  }
}

// H1 = relu(sum_z T[z] + bias), written DIRECTLY as packed bf16 hi/lo tiles
__global__ __launch_bounds__(256) void combine8_relu_pack(
    const float* __restrict__ T, const float* __restrict__ bias,
    unsigned short* __restrict__ Oh, unsigned short* __restrict__ Ol) {
  const int e = (blockIdx.x * 256 + threadIdx.x) * 8;   // element idx in [1024x1024]
  const int MN = NROWS * REP;
  float s[8];
  {
    float4 a0 = *(const float4*)&T[e];
    float4 a1 = *(const float4*)&T[e + 4];
    s[0] = a0.x; s[1] = a0.y; s[2] = a0.z; s[3] = a0.w;
    s[4] = a1.x; s[5] = a1.y; s[6] = a1.z; s[7] = a1.w;
  }
#pragma unroll
  for (int z = 1; z < 8; ++z) {
    float4 a0 = *(const float4*)&T[z * MN + e];
    float4 a1 = *(const float4*)&T[z * MN + e + 4];
    s[0] += a0.x; s[1] += a0.y; s[2] += a0.z; s[3] += a0.w;
    s[4] += a1.x; s[5] += a1.y; s[6] += a1.z; s[7] += a1.w;
  }
  const int c0 = e & 1023;
  float4 b0 = *(const float4*)&bias[c0];
  float4 b1 = *(const float4*)&bias[c0 + 4];
  s[0] = fmaxf(s[0] + b0.x, 0.f); s[1] = fmaxf(s[1] + b0.y, 0.f);
  s[2] = fmaxf(s[2] + b0.z, 0.f); s[3] = fmaxf(s[3] + b0.w, 0.f);
  s[4] = fmaxf(s[4] + b1.x, 0.f); s[5] = fmaxf(s[5] + b1.y, 0.f);
  s[6] = fmaxf(s[6] + b1.z, 0.f); s[7] = fmaxf(s[7] + b1.w, 0.f);
  unsigned short hh[8], ll[8];
#pragma unroll
  for (int j = 0; j < 8; ++j) {
    hh[j] = rne_bf16(s[j]);
    ll[j] = rne_bf16(s[j] - bf16f(hh[j]));
  }
  const int r = e >> 10;
  const int kb = c0 >> 5, slot = (c0 >> 3) & 3;
  const int rb = r >> 7, rr = r & 127;
  size_t chunk = ((size_t)(rb * 32 + kb)) * 512 + rr * 4 + swz(rr, slot);
  unsigned short* dh = Oh + chunk * 8;
  unsigned short* dl = Ol + chunk * 8;
  *(ushort4*)dh = make_ushort4(hh[0], hh[1], hh[2], hh[3]);
  *(ushort4*)(dh + 4) = make_ushort4(hh[4], hh[5], hh[6], hh[7]);
  *(ushort4*)dl = make_ushort4(ll[0], ll[1], ll[2], ll[3]);
  *(ushort4*)(dl + 4) = make_ushort4(ll[4], ll[5], ll[6], ll[7]);
}

// H = relu(sum_{z<nz} T[z] + bias)  (fp32 out, runtime nz)
__global__ __launch_bounds__(256) void combineN_relu(
    const float* __restrict__ T, const float* __restrict__ bias,
    float* __restrict__ H, int nz) {
  const int i = blockIdx.x * 256 + threadIdx.x;
  const int MN4 = NROWS * REP / 4;
  const float4* t = (const float4*)T;
  float4 s0 = t[i];
  for (int z = 1; z < nz; ++z) {
    float4 v = t[i + z * MN4];
    s0.x += v.x; s0.y += v.y; s0.z += v.z; s0.w += v.w;
  }
  float4 bs = ((const float4*)bias)[i & 255];
  float4 r;
  r.x = fmaxf(s0.x + bs.x, 0.f);
  r.y = fmaxf(s0.y + bs.y, 0.f);
  r.z = fmaxf(s0.z + bs.z, 0.f);
  r.w = fmaxf(s0.w + bs.w, 0.f);
  ((float4*)H)[i] = r;
}

// ---------- mid-path GEMM (round-5 verified): A fp32 converted in-kernel, B packed ----------
__global__ __launch_bounds__(256) void gemm_pk(
    const float* __restrict__ A, const unsigned short* __restrict__ Bh,
    const unsigned short* __restrict__ Bl, float* __restrict__ T,
    int K, int nKB, int stepsPerZ) {
  __shared__ __align__(16) unsigned short lds[2][4][4096];
  const int tid = threadIdx.x;
  const int w = tid >> 6, l = tid & 63;
  const int bm = blockIdx.x * 128;
  const int bnb = blockIdx.y;
  const int tk0 = blockIdx.z * stepsPerZ;
  const int arow = tid >> 1, ahalf = tid & 1;
  const int fr = l & 15, q = l >> 4;
  const int wr = (w >> 1) * 64, wc = (w & 1) * 64;
  const int qs = q ^ (fr & 3) ^ (fr >> 2);
  const int aoff = ((wr + fr) * 4 + qs) * 16;
  const int boff = ((wc + fr) * 4 + qs) * 16;
  const float* aptr = A + (size_t)(bm + arow) * K + ahalf * 16;

  float4 av[4];
  auto loadA = [&](int tk) {
    const float* p = aptr + tk * 32;
#pragma unroll
    for (int j = 0; j < 4; ++j) av[j] = *(const float4*)(p + j * 4);
  };
  auto stageB = [&](int bf, int tk) {
    const unsigned short* gh = Bh + ((size_t)(bnb * nKB + tk)) * 4096;
    const unsigned short* gl_ = Bl + ((size_t)(bnb * nKB + tk)) * 4096;
#pragma unroll
    for (int rseg = 0; rseg < 2; ++rseg) {
      const int seg = rseg * 4 + w;
      gload16(gh + (size_t)(seg * 64 + l) * 8, &lds[bf][2][seg * 512]);
      gload16(gl_ + (size_t)(seg * 64 + l) * 8, &lds[bf][3][seg * 512]);
    }
  };
  auto writeA = [&](int bf) {
#pragma unroll
    for (int j = 0; j < 2; ++j) {
      const int s_ = ahalf * 2 + j;
      float fv[8] = {av[j * 2].x, av[j * 2].y, av[j * 2].z, av[j * 2].w,
                     av[j * 2 + 1].x, av[j * 2 + 1].y, av[j * 2 + 1].z, av[j * 2 + 1].w};
      unsigned hp[4], lp[4];
#pragma unroll
      for (int p2 = 0; p2 < 4; ++p2) {
        unsigned short h0 = rne_bf16(fv[2 * p2]), h1 = rne_bf16(fv[2 * p2 + 1]);
        float l0 = fv[2 * p2] - bf16f(h0), l1 = fv[2 * p2 + 1] - bf16f(h1);
        hp[p2] = (unsigned)h0 | ((unsigned)h1 << 16);
        lp[p2] = (unsigned)rne_bf16(l0) | ((unsigned)rne_bf16(l1) << 16);
      }
      const int chunk = arow * 4 + swz(arow, s_);
      *(uint4*)&lds[bf][0][chunk * 8] = make_uint4(hp[0], hp[1], hp[2], hp[3]);
      *(uint4*)&lds[bf][1][chunk * 8] = make_uint4(lp[0], lp[1], lp[2], lp[3]);
    }
  };

  f32x4 acc[4][4];
#pragma unroll
  for (int m = 0; m < 4; ++m)
#pragma unroll
    for (int n = 0; n < 4; ++n) acc[m][n] = (f32x4){0.f, 0.f, 0.f, 0.f};

  loadA(tk0);
  stageB(0, tk0);
  writeA(0);
  __syncthreads();
  int cur = 0;
  for (int s = 0; s < stepsPerZ; ++s) {
    const bool nx = (s + 1 < stepsPerZ);
    if (nx) { loadA(tk0 + s + 1); stageB(cur ^ 1, tk0 + s + 1); }
    const char* La = (const char*)&lds[cur][0][0];
    const char* Ll = (const char*)&lds[cur][1][0];
    const char* Lbh = (const char*)&lds[cur][2][0];
    const char* Lbl = (const char*)&lds[cur][3][0];
    bf16x8 ah[4], al[4], bh[4], bl[4];
#pragma unroll
    for (int m = 0; m < 4; ++m) {
      ah[m] = *(const bf16x8*)(La + aoff + m * 1024);
      al[m] = *(const bf16x8*)(Ll + aoff + m * 1024);
    }
#pragma unroll
    for (int n = 0; n < 4; ++n) {
      bh[n] = *(const bf16x8*)(Lbh + boff + n * 1024);
      bl[n] = *(const bf16x8*)(Lbl + boff + n * 1024);
    }
#pragma unroll
    for (int m = 0; m < 4; ++m)
#pragma unroll
      for (int n = 0; n < 4; ++n) {
        acc[m][n] = __builtin_amdgcn_mfma_f32_16x16x32_bf16(ah[m], bh[n], acc[m][n], 0, 0, 0);
        acc[m][n] = __builtin_amdgcn_mfma_f32_16x16x32_bf16(ah[m], bl[n], acc[m][n], 0, 0, 0);
        acc[m][n] = __builtin_amdgcn_mfma_f32_16x16x32_bf16(al[m], bh[n], acc[m][n], 0, 0, 0);
      }
    if (nx) writeA(cur ^ 1);
    __syncthreads();
    cur ^= 1;
  }
  float* Tz = T + (size_t)blockIdx.z * (NROWS * REP);
#pragma unroll
  for (int m = 0; m < 4; ++m) {
    const int r0 = bm + wr + m * 16 + ((l >> 4) << 2);
#pragma unroll
    for (int n = 0; n < 4; ++n) {
      const int c = bnb * 128 + wc + n * 16 + fr;
#pragma unroll
      for (int j = 0; j < 4; ++j) Tz[(size_t)(r0 + j) * REP + c] = acc[m][n][j];
    }
  }
}

// ---------------- legacy fp32 GEMM (fallback when ws is small) ----------------
__global__ __launch_bounds__(256) void gemm64(
    const float* __restrict__ A, const float* __restrict__ W,
    float* __restrict__ T, int K, int N, int kChunk) {
  __shared__ float As[32][68];
  __shared__ float Bs[32][64];
  const int tid = threadIdx.x;
  const int bm = blockIdx.x * 64, bn = blockIdx.y * 64;
  const int k0 = blockIdx.z * kChunk;
  const int tx = tid & 15, ty = tid >> 4;
  const int ar = tid >> 3;
  const int ac = (tid & 7) << 2;
  const int br = tid >> 4;
  const int bc = (tid & 15) << 2;
  float acc[4][4] = {{0.f,0.f,0.f,0.f},{0.f,0.f,0.f,0.f},{0.f,0.f,0.f,0.f},{0.f,0.f,0.f,0.f}};
  for (int kk = k0; kk < k0 + kChunk; kk += 32) {
    float4 a0 = *(const float4*)&A[(size_t)(bm + ar) * K + kk + ac];
    float4 a1 = *(const float4*)&A[(size_t)(bm + ar + 32) * K + kk + ac];
    float4 b0 = *(const float4*)&W[(size_t)(kk + br) * N + bn + bc];
    float4 b1 = *(const float4*)&W[(size_t)(kk + br + 16) * N + bn + bc];
    As[ac+0][ar] = a0.x; As[ac+1][ar] = a0.y; As[ac+2][ar] = a0.z; As[ac+3][ar] = a0.w;
    As[ac+0][ar+32] = a1.x; As[ac+1][ar+32] = a1.y; As[ac+2][ar+32] = a1.z; As[ac+3][ar+32] = a1.w;
    *(float4*)&Bs[br][bc]    = b0;
    *(float4*)&Bs[br+16][bc] = b1;
    __syncthreads();
#pragma unroll
    for (int k = 0; k < 32; ++k) {
      float4 av = *(const float4*)&As[k][ty << 2];
      float4 bv = *(const float4*)&Bs[k][tx << 2];
      float a_[4] = {av.x, av.y, av.z, av.w};
      float b_[4] = {bv.x, bv.y, bv.z, bv.w};
#pragma unroll
      for (int i = 0; i < 4; ++i)
#pragma unroll
        for (int j = 0; j < 4; ++j)
          acc[i][j] = fmaf(a_[i], b_[j], acc[i][j]);
    }
    __syncthreads();
  }
  float* Tz = T + (size_t)blockIdx.z * NROWS * REP;
#pragma unroll
  for (int i = 0; i < 4; ++i) {
    float4 v = make_float4(acc[i][0], acc[i][1], acc[i][2], acc[i][3]);
    *(float4*)&Tz[(size_t)(bm + (ty << 2) + i) * N + bn + (tx << 2)] = v;
  }
}

// ---------- fused heads: wave-per-row, coalesced Wt reads, shfl reduce, softmax+decode ----------
__global__ __launch_bounds__(256) void heads2(
    const float* __restrict__ H2, const float* __restrict__ Wt,
    const float* __restrict__ bcv, const float* __restrict__ bbv,
    const float* __restrict__ props, float* __restrict__ pb, float* __restrict__ sc) {
  const int wave = threadIdx.x >> 6, l = threadIdx.x & 63;
  const int n = blockIdx.x * 4 + wave;
  const float* h = H2 + (size_t)n * REP + l * 16;
  float4 h0 = *(const float4*)h, h1 = *(const float4*)(h + 4);
  float4 h2v = *(const float4*)(h + 8), h3 = *(const float4*)(h + 12);
  float outv[25];
#pragma unroll
  for (int o = 0; o < 25; ++o) {
    const float* wp = Wt + o * REP + l * 16;
    float4 w0 = *(const float4*)wp, w1 = *(const float4*)(wp + 4);
    float4 w2 = *(const float4*)(wp + 8), w3 = *(const float4*)(wp + 12);
    float d = h0.x * w0.x;
    d = fmaf(h0.y, w0.y, d); d = fmaf(h0.z, w0.z, d); d = fmaf(h0.w, w0.w, d);
    d = fmaf(h1.x, w1.x, d); d = fmaf(h1.y, w1.y, d); d = fmaf(h1.z, w1.z, d); d = fmaf(h1.w, w1.w, d);
    d = fmaf(h2v.x, w2.x, d); d = fmaf(h2v.y, w2.y, d); d = fmaf(h2v.z, w2.z, d); d = fmaf(h2v.w, w2.w, d);
    d = fmaf(h3.x, w3.x, d); d = fmaf(h3.y, w3.y, d); d = fmaf(h3.z, w3.z, d); d = fmaf(h3.w, w3.w, d);
#pragma unroll
    for (int m = 1; m < 64; m <<= 1) d += __shfl_xor(d, m);
    outv[o] = d + ((o < 5) ? bcv[o] : bbv[o - 5]);
  }
  const float mx = fmaxf(fmaxf(fmaxf(outv[0], outv[1]), fmaxf(outv[2], outv[3])), outv[4]);
  const float e0 = expf(outv[0] - mx), e1 = expf(outv[1] - mx), e2 = expf(outv[2] - mx);
  const float e3 = expf(outv[3] - mx), e4 = expf(outv[4] - mx);
  const float inv = 1.0f / (e0 + e1 + e2 + e3 + e4);
  const float s1 = e1 * inv, s2 = e2 * inv, s3 = e3 * inv, s4 = e4 * inv;
  const float* pr = props + (size_t)n * 4;
  const float x1 = pr[0], y1 = pr[1], x2 = pr[2], y2 = pr[3];
  const float bw = x2 - x1, bh = y2 - y1;
  const float cx = x1 + 0.5f * bw, cy = y1 + 0.5f * bh;
  const int img = n >> 9, pbase = (n & 511) << 2;
#pragma unroll
  for (int c = 1; c <= 4; ++c) {
    if (l == c - 1) {
      const float r0 = outv[5 + c * 4 + 0], r1 = outv[5 + c * 4 + 1];
      const float r2 = outv[5 + c * 4 + 2], r3 = outv[5 + c * 4 + 3];
      const float dx = r0 / 10.0f, dy = r1 / 10.0f;
      const float dw = fminf(r2 / 5.0f, BBOX_CLIP_F);
      const float dh = fminf(r3 / 5.0f, BBOX_CLIP_F);
      const float pcx = dx * bw + cx, pcy = dy * bh + cy;
      const float pw = expf(dw) * bw, ph = expf(dh) * bh;
      float bx1 = pcx - 0.5f * pw, by1 = pcy - 0.5f * ph;
      float bx2 = pcx + 0.5f * pw, by2 = pcy + 0.5f * ph;
      bx1 = fminf(fmaxf(bx1, 0.f), 800.f);
      by1 = fminf(fmaxf(by1, 0.f), 800.f);
      bx2 = fminf(fmaxf(bx2, 0.f), 800.f);
      by2 = fminf(fmaxf(by2, 0.f), 800.f);
      const int pidx = pbase + (c - 1);
      float* o = pb + (size_t)(img * NDET + pidx) * 4;
      o[0] = bx1; o[1] = by1; o[2] = bx2; o[3] = by2;
      const float smc = (c == 1) ? s1 : (c == 2) ? s2 : (c == 3) ? s3 : s4;
      sc[img * NDET + pidx] = smc;
    }
  }
}

// Per proposal row (fallback paths): 25 head outputs, softmax, decode+clip
__global__ __launch_bounds__(256) void heads_kernel(
    const float* __restrict__ H2, const float* __restrict__ Wc, const float* __restrict__ bcv,
    const float* __restrict__ Wb, const float* __restrict__ bbv,
    const float* __restrict__ props, float* __restrict__ pb, float* __restrict__ sc) {
  const int n = blockIdx.x;
  __shared__ float hrow[REP];
  __shared__ float part[25][8];
  __shared__ float outv[25];
  __shared__ float smax[5];
  const int tid = threadIdx.x;
  ((float4*)hrow)[tid] = ((const float4*)(H2 + (size_t)n * REP))[tid];
  __syncthreads();
  if (tid < 200) {
    const int o = tid >> 3, s = tid & 7;
    float a = 0.f;
    if (o < 5) {
      const float* w = Wc + o;
      for (int k = s * 128; k < s * 128 + 128; ++k) a = fmaf(hrow[k], w[(size_t)k * 5], a);
    } else {
      const float* w = Wb + (o - 5);
      for (int k = s * 128; k < s * 128 + 128; ++k) a = fmaf(hrow[k], w[(size_t)k * 20], a);
    }
    part[o][s] = a;
  }
  __syncthreads();
  if (tid < 25) {
    float a = ((part[tid][0] + part[tid][1]) + (part[tid][2] + part[tid][3]))
            + ((part[tid][4] + part[tid][5]) + (part[tid][6] + part[tid][7]));
    a += (tid < 5) ? bcv[tid] : bbv[tid - 5];
    outv[tid] = a;
  }
  __syncthreads();
  if (tid == 0) {
    float m = outv[0];
    for (int c = 1; c < 5; ++c) m = fmaxf(m, outv[c]);
    float e[5], ssum = 0.f;
    for (int c = 0; c < 5; ++c) { e[c] = expf(outv[c] - m); ssum += e[c]; }
    for (int c = 0; c < 5; ++c) smax[c] = e[c] / ssum;
  }
  __syncthreads();
  if (tid < 4) {
    const int c = tid + 1;
    const float* pr = props + (size_t)n * 4;
    const float x1 = pr[0], y1 = pr[1], x2 = pr[2], y2 = pr[3];
    const float w = x2 - x1, h = y2 - y1;
    const float cx = x1 + 0.5f * w, cy = y1 + 0.5f * h;
    const float r0 = outv[5 + c * 4 + 0], r1 = outv[5 + c * 4 + 1];
    const float r2 = outv[5 + c * 4 + 2], r3 = outv[5 + c * 4 + 3];
    const float dx = r0 / 10.0f, dy = r1 / 10.0f;
    const float dw = fminf(r2 / 5.0f, BBOX_CLIP_F);
    const float dh = fminf(r3 / 5.0f, BBOX_CLIP_F);
    const float pcx = dx * w + cx, pcy = dy * h + cy;
    const float pw = expf(dw) * w, ph = expf(dh) * h;
    float bx1 = pcx - 0.5f * pw, by1 = pcy - 0.5f * ph;
    float bx2 = pcx + 0.5f * pw, by2 = pcy + 0.5f * ph;
    bx1 = fminf(fmaxf(bx1, 0.f), 800.f);
    by1 = fminf(fmaxf(by1, 0.f), 800.f);
    bx2 = fminf(fmaxf(bx2, 0.f), 800.f);
    by2 = fminf(fmaxf(by2, 0.f), 800.f);
    const int img = n >> 9;
    const int pidx = ((n & 511) << 2) + (c - 1);
    float* o = pb + (size_t)(img * NDET + pidx) * 4;
    o[0] = bx1; o[1] = by1; o[2] = bx2; o[3] = by2;
    sc[img * NDET + pidx] = smax[c];
  }
}

// ---------- fused: stable descending bitonic sort + prep (gather, valid bits, offsets) ----------
__global__ __launch_bounds__(1024) void sortprep_kernel(
    const float* __restrict__ sc, const float* __restrict__ pb,
    float* __restrict__ sbox, float* __restrict__ soff, float* __restrict__ sscore,
    float* __restrict__ sarea, float* __restrict__ slab, unsigned* __restrict__ vword) {
  const int b = blockIdx.x;
  __shared__ unsigned long long key[NDET];
  const int tid = threadIdx.x;
  for (int t = tid; t < NDET; t += 1024) {
    unsigned bits = __float_as_uint(sc[b * NDET + t]);   // scores > 0 -> monotonic
    key[t] = ((unsigned long long)bits << 32) | (unsigned)(~t);
  }
  __syncthreads();
  for (int k = 2; k <= NDET; k <<= 1) {
    for (int j = k >> 1; j > 0; j >>= 1) {
      for (int t = tid; t < NDET; t += 1024) {
        const int ixj = t ^ j;
        if (ixj > t) {
          const bool up = (t & k) == 0;
          unsigned long long a = key[t], bb_ = key[ixj];
          if ((a < bb_) == up) { key[t] = bb_; key[ixj] = a; }
        }
      }
      __syncthreads();
    }
  }
  for (int pass = 0; pass < 2; ++pass) {
    const int i = pass * 1024 + tid;
    const unsigned oi = ~(unsigned)key[i];
    const float* bx = pb + (size_t)(b * NDET + oi) * 4;
    const float x1 = bx[0], y1 = bx[1], x2 = bx[2], y2 = bx[3];
    const float s = sc[b * NDET + oi];
    const float lab = (float)((oi & 3) + 1);
    const bool valid = (s > 0.05f) && ((x2 - x1) >= 0.01f) && ((y2 - y1) >= 0.01f);
    const float off = lab * 801.0f;
    float* sb = sbox + (size_t)(b * NDET + i) * 4;
    sb[0] = x1; sb[1] = y1; sb[2] = x2; sb[3] = y2;
    float* so = soff + (size_t)(b * NDET + i) * 4;
    so[0] = x1 + off; so[1] = y1 + off; so[2] = x2 + off; so[3] = y2 + off;
    sscore[b * NDET + i] = s;
    sarea[b * NDET + i] = (x2 - x1) * (y2 - y1);
    slab[b * NDET + i] = lab;
    const unsigned long long bal = __ballot(valid);
    if ((i & 31) == 0) vword[b * 64 + (i >> 5)] = (unsigned)(bal >> (i & 32));
  }
}

// Suppression bitmask, CONTIGUOUS layout: word w of row i covers rows [w*32, w*32+32)
__global__ __launch_bounds__(256) void mask_kernel(
    const float* __restrict__ soff, const float* __restrict__ sarea,
    unsigned* __restrict__ mask) {
  const int b = blockIdx.y;
  __shared__ float xx1[NDET + 64], yy1[NDET + 64], xx2[NDET + 64], yy2[NDET + 64];
  __shared__ float ar[NDET + 64];
  const int tid = threadIdx.x;
  for (int t = tid; t < NDET; t += 256) {
    float4 v = *(const float4*)(soff + ((size_t)b * NDET + t) * 4);
    const int pt = t + (t >> 5);
    xx1[pt] = v.x; yy1[pt] = v.y; xx2[pt] = v.z; yy2[pt] = v.w;
    ar[pt] = sarea[b * NDET + t];
  }
  __syncthreads();
  const int li = tid >> 6;
  const int w  = tid & 63;
#pragma unroll
  for (int pass = 0; pass < 4; ++pass) {
    const int i = blockIdx.x * 16 + pass * 4 + li;
    const int pi = i + (i >> 5);
    const float ax1 = xx1[pi], ay1 = yy1[pi], ax2 = xx2[pi], ay2 = yy2[pi];
    const float aa = ar[pi];
    unsigned bits = 0;
#pragma unroll 4
    for (int bb = 0; bb < 32; ++bb) {
      const int j = w * 32 + bb;
      const int pj = w * 33 + bb;
      const float ix = fmaxf(fminf(ax2, xx2[pj]) - fmaxf(ax1, xx1[pj]), 0.f);
      const float iy = fmaxf(fminf(ay2, yy2[pj]) - fmaxf(ay1, yy1[pj]), 0.f);
      const float inter = ix * iy;
      const float iou = inter / (aa + ar[pj] - inter + 1e-9f);
      if (j > i && iou > 0.5f) bits |= (1u << bb);
    }
    mask[((size_t)b * NDET + i) * 64 + w] = bits;
  }
}

// Greedy NMS scan: suppression word in REGISTER per lane; shfl (no LDS/barrier) per keep.
__global__ __launch_bounds__(64) void scan_kernel(
    const unsigned* __restrict__ vword, const unsigned* __restrict__ mask,
    const float* __restrict__ sbox, const float* __restrict__ sscore,
    const float* __restrict__ slab, float* __restrict__ out) {
  const int b = blockIdx.x;
  const int lane = threadIdx.x;
  unsigned supreg = ~vword[b * 64 + lane];   // invalid rows pre-suppressed
  __shared__ unsigned short klist[DETS];
  int kcnt = 0;
  for (int w = 0; w < 64 && kcnt < DETS; ++w) {
    unsigned avail = ~__shfl(supreg, w);
    while (avail) {
      const int bb = __ffs(avail) - 1;
      const int i = w * 32 + bb;
      if (lane == 0) klist[kcnt] = (unsigned short)i;
      kcnt++;
      if (kcnt == DETS) break;
      supreg |= mask[((size_t)b * NDET + i) * 64 + lane];
      avail = ~__shfl(supreg, w) & (0xFFFFFFFEu << bb);
    }
  }
  __syncthreads();
  for (int s = lane; s < DETS; s += 64) {
    float b0 = 0.f, b1 = 0.f, b2 = 0.f, b3 = 0.f, sv = 0.f, lv = 0.f;
    if (s < kcnt) {
      const int i = klist[s];
      const float* bx = sbox + ((size_t)b * NDET + i) * 4;
      b0 = bx[0]; b1 = bx[1]; b2 = bx[2]; b3 = bx[3];
      sv = sscore[b * NDET + i];
      lv = slab[b * NDET + i];
    }
    float* ob = out + ((size_t)b * DETS + s) * 4;
    ob[0] = b0; ob[1] = b1; ob[2] = b2; ob[3] = b3;
    out[2 * DETS * 4 + b * DETS + s] = sv;
    out[2 * DETS * 4 + 2 * DETS + b * DETS + s] = lv;
  }
}

extern "C" void kernel_launch(void* const* d_in, const int* in_sizes, int n_in,
                              void* d_out, int out_size, void* d_ws, size_t ws_size,
                              hipStream_t stream) {
  const float* X     = (const float*)d_in[0];
  const float* props = (const float*)d_in[1];
  const float* W1    = (const float*)d_in[2];
  const float* b1    = (const float*)d_in[3];
  const float* W2    = (const float*)d_in[4];
  const float* b2    = (const float*)d_in[5];
  const float* Wc    = (const float*)d_in[6];
  const float* bc    = (const float*)d_in[7];
  const float* Wb    = (const float*)d_in[8];
  const float* bb    = (const float*)d_in[9];
  float* out = (float*)d_out;

  const size_t POST_B = 3200000;
  const size_t NEED_BIG =
      (size_t)9 * 1048576 * 4 +
      (size_t)4 * (size_t)K1 * 1024 * 2 +
      (size_t)4 * 1048576 * 2 + POST_B;
  const size_t NEED_MID =
      (size_t)10 * 1048576 * 4 +
      (size_t)2 * (size_t)K1 * 1024 * 2 +
      (size_t)2 * 1048576 * 2 + 2500000;

  float *T, *H1 = nullptr, *H2, *pb, *sc, *Wt = nullptr;
  unsigned short *W1h = nullptr, *W1l = nullptr, *W2h = nullptr, *W2l = nullptr;
  unsigned short *Ahp = nullptr, *Alp = nullptr, *H1h = nullptr, *H1l = nullptr;
  const int path = (ws_size >= NEED_BIG) ? 2 : (ws_size >= NEED_MID) ? 1 : 0;
  if (path == 2) {
    T   = (float*)d_ws;                  // 8 * 1048576
    H2  = T + 8 * 1048576;
    W1h = (unsigned short*)(H2 + 1048576);
    W1l = W1h + (size_t)K1 * 1024;
    W2h = W1l + (size_t)K1 * 1024;
    W2l = W2h + 1048576;
    Ahp = W2l + 1048576;
    Alp = Ahp + (size_t)K1 * 1024;
    H1h = Alp + (size_t)K1 * 1024;
    H1l = H1h + 1048576;
    Wt  = (float*)(H1l + 1048576);       // 25*1024 floats
    pb  = Wt + 25 * 1024;
  } else if (path == 1) {
    T   = (float*)d_ws;
    H1  = T + 8 * 1048576;
    H2  = H1 + 1048576;
    W1h = (unsigned short*)(H2 + 1048576);
    W1l = W1h + (size_t)K1 * 1024;
    W2h = W1l + (size_t)K1 * 1024;
    W2l = W2h + 1048576;
    pb  = (float*)(W2l + 1048576);
  } else {
    T  = (float*)d_ws;
    H1 = T + 4 * 1048576;
    H2 = H1 + 1048576;
    pb = H2 + 1048576;
  }
  sc = pb + 2 * NDET * 4;
  unsigned* sidx = (unsigned*)(sc + 2 * NDET);   // kept for layout stability (unused)
  float* sbox   = (float*)(sidx + 2 * NDET);
  float* soff   = sbox + 2 * NDET * 4;
  float* sscore = soff + 2 * NDET * 4;
  float* sarea  = sscore + 2 * NDET;
  float* slab   = sarea + 2 * NDET;
  unsigned* vword = (unsigned*)(slab + 2 * NDET);
  unsigned* mask  = vword + 128;

  if (path == 2) {
    pack_fused<<<19940, 256, 0, stream>>>(X, W1, W2, Wc, Wb,
                                          Ahp, Alp, W1h, W1l, W2h, W2l, Wt);
    gemm_pk2<<<dim3(8, 8, 8), 256, 0, stream>>>(Ahp, Alp, W1h, W1l, T, K1 / 32, 49);
    combine8_relu_pack<<<512, 256, 0, stream>>>(T, b1, H1h, H1l);
    gemm_pk2<<<dim3(8, 8, 4), 256, 0, stream>>>(H1h, H1l, W2h, W2l, T, 32, 8);
    combineN_relu<<<1024, 256, 0, stream>>>(T, b2, H2, 4);
    heads2<<<256, 256, 0, stream>>>(H2, Wt, bc, bb, props, pb, sc);
  } else if (path == 1) {
    pack_b<<<dim3(K1 / 32, 32), 256, 0, stream>>>(W1, W1h, W1l, K1 / 32);
    pack_b<<<dim3(32, 32), 256, 0, stream>>>(W2, W2h, W2l, 32);
    gemm_pk<<<dim3(8, 8, 8), 256, 0, stream>>>(X, W1h, W1l, T, K1, K1 / 32, 49);
    combineN_relu<<<1024, 256, 0, stream>>>(T, b1, H1, 8);
    gemm_pk<<<dim3(8, 8, 4), 256, 0, stream>>>(H1, W2h, W2l, T, REP, 32, 8);
    combineN_relu<<<1024, 256, 0, stream>>>(T, b2, H2, 4);
    heads_kernel<<<1024, 256, 0, stream>>>(H2, Wc, bc, Wb, bb, props, pb, sc);
  } else {
    gemm64<<<dim3(16, 16, 4), 256, 0, stream>>>(X, W1, T, K1, REP, K1 / 4);
    combineN_relu<<<1024, 256, 0, stream>>>(T, b1, H1, 4);
    gemm64<<<dim3(16, 16, 4), 256, 0, stream>>>(H1, W2, T, REP, REP, REP / 4);
    combineN_relu<<<1024, 256, 0, stream>>>(T, b2, H2, 4);
    heads_kernel<<<1024, 256, 0, stream>>>(H2, Wc, bc, Wb, bb, props, pb, sc);
  }
  sortprep_kernel<<<2, 1024, 0, stream>>>(sc, pb, sbox, soff, sscore, sarea, slab, vword);
  mask_kernel<<<dim3(128, 2), 256, 0, stream>>>(soff, sarea, mask);
  scan_kernel<<<2, 64, 0, stream>>>(vword, mask, sbox, sscore, slab, out);
}

// Round 16
// 218.792 us; speedup vs baseline: 1.0806x; 1.0537x over previous
//
#include <hip/hip_runtime.h>
#include <math.h>

#define NROWS 1024      // B*P
#define K1    12544
#define REP   1024
#define NDET  2048      // P*(C-1)
#define DETS  100
#define BBOX_CLIP_F 4.135166556742356f

typedef __attribute__((ext_vector_type(8))) short bf16x8;
typedef __attribute__((ext_vector_type(4))) float f32x4;

__device__ __forceinline__ unsigned short rne_bf16(float x) {
  unsigned u = __float_as_uint(x);
  u += 0x7fffu + ((u >> 16) & 1u);
  return (unsigned short)(u >> 16);
}
__device__ __forceinline__ float bf16f(unsigned short h) {
  return __uint_as_float(((unsigned)h) << 16);
}
// chunk swizzle: slot s of row r lives at chunk r*4 + SWZ(r,s) within an 8KB tile
__device__ __forceinline__ int swz(int r, int s) {
  return s ^ (r & 3) ^ ((r >> 2) & 3);
}
__device__ __forceinline__ void gload16(const void* g, void* lds) {
  __builtin_amdgcn_global_load_lds(
      (const __attribute__((address_space(1))) unsigned int*)g,
      (__attribute__((address_space(3))) unsigned int*)lds, 16, 0, 0);
}

// ---------- fused pack: W1, W2 (transpose-pack), A (row-pack), Wt (25x1024) ----------
// grid = 12544 (W1) + 1024 (W2) + 6272 (A) + 100 (Wt) = 19940 blocks x 256
__global__ __launch_bounds__(256) void pack_fused(
    const float* __restrict__ X, const float* __restrict__ W1,
    const float* __restrict__ W2, const float* __restrict__ Wc,
    const float* __restrict__ Wb,
    unsigned short* __restrict__ Ahp, unsigned short* __restrict__ Alp,
    unsigned short* __restrict__ W1h, unsigned short* __restrict__ W1l,
    unsigned short* __restrict__ W2h, unsigned short* __restrict__ W2l,
    float* __restrict__ Wt) {
  __shared__ unsigned short th[32 * 36], tl[32 * 36];
  const int id = blockIdx.x;
  const int t = threadIdx.x;
  if (id < 13568) {
    // ---- pack_b for W1 (nKB=392) or W2 (nKB=32) ----
    const float* W;
    unsigned short *Oh, *Ol;
    int nKB, kb, n0;
    if (id < 12544) { W = W1; Oh = W1h; Ol = W1l; nKB = 392; kb = id % 392; n0 = (id / 392) * 32; }
    else { const int r2 = id - 12544; W = W2; Oh = W2h; Ol = W2l; nKB = 32; kb = r2 % 32; n0 = (r2 / 32) * 32; }
    const int r = t >> 3, c4 = (t & 7) << 2;          // r = k_local
    float4 v = *(const float4*)&W[(size_t)(kb * 32 + r) * REP + n0 + c4];
    float fv[4] = {v.x, v.y, v.z, v.w};
#pragma unroll
    for (int j = 0; j < 4; ++j) {
      unsigned short h = rne_bf16(fv[j]);
      th[(c4 + j) * 36 + r] = h;
      tl[(c4 + j) * 36 + r] = rne_bf16(fv[j] - bf16f(h));
    }
    __syncthreads();
    const int half = t >> 7;                           // 0 -> h, 1 -> l
    const int n_loc = (t & 127) >> 2, slot = t & 3;
    const unsigned short* src = (half ? tl : th) + n_loc * 36 + slot * 8;
    ushort4 u0 = *(const ushort4*)src;
    ushort4 u1 = *(const ushort4*)(src + 4);
    const int n = n0 + n_loc, rb = n >> 7, rr = n & 127;
    size_t chunk = ((size_t)(rb * nKB + kb)) * 512 + rr * 4 + swz(rr, slot);
    unsigned short* dst = (half ? Ol : Oh) + chunk * 8;
    *(ushort4*)dst = u0;
    *(ushort4*)(dst + 4) = u1;
  } else if (id < 19840) {
    // ---- pack_a for X (nKB=392) ----
    const int r_ = id - 13568;
    const int kb = r_ % 392;
    const int row = (r_ / 392) * 64 + (t >> 2);
    const int slot = t & 3;
    const float* p = X + (size_t)row * K1 + kb * 32 + slot * 8;
    float4 f0 = *(const float4*)p;
    float4 f1 = *(const float4*)(p + 4);
    float fv[8] = {f0.x, f0.y, f0.z, f0.w, f1.x, f1.y, f1.z, f1.w};
    unsigned short hh[8], ll[8];
#pragma unroll
    for (int j = 0; j < 8; ++j) {
      hh[j] = rne_bf16(fv[j]);
      ll[j] = rne_bf16(fv[j] - bf16f(hh[j]));
    }
    const int rb = row >> 7, rr = row & 127;
    size_t chunk = ((size_t)(rb * 392 + kb)) * 512 + rr * 4 + swz(rr, slot);
    unsigned short* dh = Ahp + chunk * 8;
    unsigned short* dl = Alp + chunk * 8;
    *(ushort4*)dh = make_ushort4(hh[0], hh[1], hh[2], hh[3]);
    *(ushort4*)(dh + 4) = make_ushort4(hh[4], hh[5], hh[6], hh[7]);
    *(ushort4*)dl = make_ushort4(ll[0], ll[1], ll[2], ll[3]);
    *(ushort4*)(dl + 4) = make_ushort4(ll[4], ll[5], ll[6], ll[7]);
  } else {
    // ---- pack_w25: Wt[25][1024] from Wc[1024][5], Wb[1024][20] ----
    const int i = (id - 19840) * 256 + t;
    if (i < 25 * 1024) {
      const int o = i >> 10, k = i & 1023;
      Wt[i] = (o < 5) ? Wc[(size_t)k * 5 + o] : Wb[(size_t)k * 20 + (o - 5)];
    }
  }
}

// ---------- standalone packs (fallback path 1) ----------
__global__ __launch_bounds__(256) void pack_b(
    const float* __restrict__ W, unsigned short* __restrict__ Oh,
    unsigned short* __restrict__ Ol, int nKB) {
  __shared__ unsigned short th[32 * 36], tl[32 * 36];
  const int kb = blockIdx.x, n0 = blockIdx.y * 32;
  const int t = threadIdx.x;
  const int r = t >> 3, c4 = (t & 7) << 2;
  float4 v = *(const float4*)&W[(size_t)(kb * 32 + r) * REP + n0 + c4];
  float fv[4] = {v.x, v.y, v.z, v.w};
#pragma unroll
  for (int j = 0; j < 4; ++j) {
    unsigned short h = rne_bf16(fv[j]);
    th[(c4 + j) * 36 + r] = h;
    tl[(c4 + j) * 36 + r] = rne_bf16(fv[j] - bf16f(h));
  }
  __syncthreads();
  const int half = t >> 7;
  const int n_loc = (t & 127) >> 2, slot = t & 3;
  const unsigned short* src = (half ? tl : th) + n_loc * 36 + slot * 8;
  ushort4 u0 = *(const ushort4*)src;
  ushort4 u1 = *(const ushort4*)(src + 4);
  const int n = n0 + n_loc, rb = n >> 7, rr = n & 127;
  size_t chunk = ((size_t)(rb * nKB + kb)) * 512 + rr * 4 + swz(rr, slot);
  unsigned short* dst = (half ? Ol : Oh) + chunk * 8;
  *(ushort4*)dst = u0;
  *(ushort4*)(dst + 4) = u1;
}

// ---------- MFMA GEMM, both operands pre-packed: T[z] = A @ B ----------
// 128x128 tile, 4 waves x (64x64 via 4x4 16x16x32 frags), BK=32, splitK via z.
// XCD tile-swizzle. COUNTED-VMCNT pipeline (T4): stage(t+2) loads stay in flight
// across both barriers; vmcnt(8) retires only the older tile's 8 loads. No full drain.
__global__ __launch_bounds__(256) void gemm_pk2(
    const unsigned short* __restrict__ Ah, const unsigned short* __restrict__ Al,
    const unsigned short* __restrict__ Bh, const unsigned short* __restrict__ Bl,
    float* __restrict__ T, int nKB, int stepsPerZ) {
  __shared__ __align__(16) unsigned short lds[2][4][4096];  // [buf][Ah,Al,Bh,Bl] 64KB
  const int tid = threadIdx.x;
  const int w = tid >> 6, l = tid & 63;
  const int r_ = blockIdx.x, t_ = blockIdx.y;        // XCD residue, slot-within-XCD
  const int rbA = (r_ & 3) * 2 + (t_ & 1);
  const int rbB = (r_ >> 2) * 4 + (t_ >> 1);
  const int tk0 = blockIdx.z * stepsPerZ;
  const int fr = l & 15, q = l >> 4;
  const int wr = (w >> 1) * 64, wc = (w & 1) * 64;
  const int qs = q ^ (fr & 3) ^ (fr >> 2);           // per-lane-constant read swizzle
  const int aoff = ((wr + fr) * 4 + qs) * 16;        // byte offset; +m*1024 per frag
  const int boff = ((wc + fr) * 4 + qs) * 16;

  auto stage = [&](int bf, int tk) {                 // exactly 8 gload16 per thread
    const unsigned short* ga_h = Ah + ((size_t)(rbA * nKB + tk)) * 4096;
    const unsigned short* ga_l = Al + ((size_t)(rbA * nKB + tk)) * 4096;
    const unsigned short* gb_h = Bh + ((size_t)(rbB * nKB + tk)) * 4096;
    const unsigned short* gb_l = Bl + ((size_t)(rbB * nKB + tk)) * 4096;
#pragma unroll
    for (int rseg = 0; rseg < 2; ++rseg) {
      const int seg = rseg * 4 + w;
      const size_t go = (size_t)(seg * 64 + l) * 8;
      gload16(ga_h + go, &lds[bf][0][seg * 512]);
      gload16(ga_l + go, &lds[bf][1][seg * 512]);
      gload16(gb_h + go, &lds[bf][2][seg * 512]);
      gload16(gb_l + go, &lds[bf][3][seg * 512]);
    }
  };

  f32x4 acc[4][4];
#pragma unroll
  for (int m = 0; m < 4; ++m)
#pragma unroll
    for (int n = 0; n < 4; ++n) acc[m][n] = (f32x4){0.f, 0.f, 0.f, 0.f};

  // prologue: stage both buffers; wait only buf0's 8 (the oldest)
  stage(0, tk0);
  if (stepsPerZ > 1) {
    stage(1, tk0 + 1);
    asm volatile("s_waitcnt vmcnt(8)");
  } else {
    asm volatile("s_waitcnt vmcnt(0)");
  }
  __builtin_amdgcn_s_barrier();
  __builtin_amdgcn_sched_barrier(0);

  int cur = 0;
  for (int s = 0; s < stepsPerZ; ++s) {
    const char* La  = (const char*)&lds[cur][0][0];
    const char* Ll  = (const char*)&lds[cur][1][0];
    const char* Lbh = (const char*)&lds[cur][2][0];
    const char* Lbl = (const char*)&lds[cur][3][0];
    bf16x8 ah[4], al[4], bh[4], bl[4];
#pragma unroll
    for (int m = 0; m < 4; ++m) {
      ah[m] = *(const bf16x8*)(La + aoff + m * 1024);
      al[m] = *(const bf16x8*)(Ll + aoff + m * 1024);
    }
#pragma unroll
    for (int n = 0; n < 4; ++n) {
      bh[n] = *(const bf16x8*)(Lbh + boff + n * 1024);
      bl[n] = *(const bf16x8*)(Lbl + boff + n * 1024);
    }
#pragma unroll
    for (int m = 0; m < 4; ++m)
#pragma unroll
      for (int n = 0; n < 4; ++n) {
        acc[m][n] = __builtin_amdgcn_mfma_f32_16x16x32_bf16(ah[m], bh[n], acc[m][n], 0, 0, 0);
        acc[m][n] = __builtin_amdgcn_mfma_f32_16x16x32_bf16(ah[m], bl[n], acc[m][n], 0, 0, 0);
        acc[m][n] = __builtin_amdgcn_mfma_f32_16x16x32_bf16(al[m], bh[n], acc[m][n], 0, 0, 0);
      }
    if (s + 1 < stepsPerZ) {
      __builtin_amdgcn_s_barrier();                  // (A) all waves done reading buf[cur]
      if (s + 2 < stepsPerZ) {
        stage(cur, tk0 + s + 2);                     // overwrite cur; 8 new loads flying
        asm volatile("s_waitcnt vmcnt(8)");          // retire tile t+1 (older 8)
      } else {
        asm volatile("s_waitcnt vmcnt(0)");          // tail: retire t+1 fully
      }
      __builtin_amdgcn_s_barrier();                  // (B) buf[cur^1] ready block-wide
      __builtin_amdgcn_sched_barrier(0);             // pin next ds_reads behind (B)
    }
    cur ^= 1;
  }
  // epilogue: D row = (l>>4)*4 + j, col = l&15
  float* Tz = T + (size_t)blockIdx.z * (NROWS * REP);
#pragma unroll
  for (int m = 0; m < 4; ++m) {
    const int r0 = rbA * 128 + wr + m * 16 + ((l >> 4) << 2);
#pragma unroll
    for (int n = 0; n < 4; ++n) {
      const int c = rbB * 128 + wc + n * 16 + fr;
#pragma unroll
      for (int j = 0; j < 4; ++j) Tz[(size_t)(r0 + j) * REP + c] = acc[m][n][j];
    }
  }
}

// H1 = relu(sum_z T[z] + bias), written DIRECTLY as packed bf16 hi/lo tiles
__global__ __launch_bounds__(256) void combine8_relu_pack(
    const float* __restrict__ T, const float* __restrict__ bias,
    unsigned short* __restrict__ Oh, unsigned short* __restrict__ Ol) {
  const int e = (blockIdx.x * 256 + threadIdx.x) * 8;   // element idx in [1024x1024]
  const int MN = NROWS * REP;
  float s[8];
  {
    float4 a0 = *(const float4*)&T[e];
    float4 a1 = *(const float4*)&T[e + 4];
    s[0] = a0.x; s[1] = a0.y; s[2] = a0.z; s[3] = a0.w;
    s[4] = a1.x; s[5] = a1.y; s[6] = a1.z; s[7] = a1.w;
  }
#pragma unroll
  for (int z = 1; z < 8; ++z) {
    float4 a0 = *(const float4*)&T[z * MN + e];
    float4 a1 = *(const float4*)&T[z * MN + e + 4];
    s[0] += a0.x; s[1] += a0.y; s[2] += a0.z; s[3] += a0.w;
    s[4] += a1.x; s[5] += a1.y; s[6] += a1.z; s[7] += a1.w;
  }
  const int c0 = e & 1023;
  float4 b0 = *(const float4*)&bias[c0];
  float4 b1 = *(const float4*)&bias[c0 + 4];
  s[0] = fmaxf(s[0] + b0.x, 0.f); s[1] = fmaxf(s[1] + b0.y, 0.f);
  s[2] = fmaxf(s[2] + b0.z, 0.f); s[3] = fmaxf(s[3] + b0.w, 0.f);
  s[4] = fmaxf(s[4] + b1.x, 0.f); s[5] = fmaxf(s[5] + b1.y, 0.f);
  s[6] = fmaxf(s[6] + b1.z, 0.f); s[7] = fmaxf(s[7] + b1.w, 0.f);
  unsigned short hh[8], ll[8];
#pragma unroll
  for (int j = 0; j < 8; ++j) {
    hh[j] = rne_bf16(s[j]);
    ll[j] = rne_bf16(s[j] - bf16f(hh[j]));
  }
  const int r = e >> 10;
  const int kb = c0 >> 5, slot = (c0 >> 3) & 3;
  const int rb = r >> 7, rr = r & 127;
  size_t chunk = ((size_t)(rb * 32 + kb)) * 512 + rr * 4 + swz(rr, slot);
  unsigned short* dh = Oh + chunk * 8;
  unsigned short* dl = Ol + chunk * 8;
  *(ushort4*)dh = make_ushort4(hh[0], hh[1], hh[2], hh[3]);
  *(ushort4*)(dh + 4) = make_ushort4(hh[4], hh[5], hh[6], hh[7]);
  *(ushort4*)dl = make_ushort4(ll[0], ll[1], ll[2], ll[3]);
  *(ushort4*)(dl + 4) = make_ushort4(ll[4], ll[5], ll[6], ll[7]);
}

// H = relu(sum_{z<nz} T[z] + bias)  (fp32 out, runtime nz)
__global__ __launch_bounds__(256) void combineN_relu(
    const float* __restrict__ T, const float* __restrict__ bias,
    float* __restrict__ H, int nz) {
  const int i = blockIdx.x * 256 + threadIdx.x;
  const int MN4 = NROWS * REP / 4;
  const float4* t = (const float4*)T;
  float4 s0 = t[i];
  for (int z = 1; z < nz; ++z) {
    float4 v = t[i + z * MN4];
    s0.x += v.x; s0.y += v.y; s0.z += v.z; s0.w += v.w;
  }
  float4 bs = ((const float4*)bias)[i & 255];
  float4 r;
  r.x = fmaxf(s0.x + bs.x, 0.f);
  r.y = fmaxf(s0.y + bs.y, 0.f);
  r.z = fmaxf(s0.z + bs.z, 0.f);
  r.w = fmaxf(s0.w + bs.w, 0.f);
  ((float4*)H)[i] = r;
}

// ---------- mid-path GEMM (round-5 verified): A fp32 converted in-kernel, B packed ----------
__global__ __launch_bounds__(256) void gemm_pk(
    const float* __restrict__ A, const unsigned short* __restrict__ Bh,
    const unsigned short* __restrict__ Bl, float* __restrict__ T,
    int K, int nKB, int stepsPerZ) {
  __shared__ __align__(16) unsigned short lds[2][4][4096];
  const int tid = threadIdx.x;
  const int w = tid >> 6, l = tid & 63;
  const int bm = blockIdx.x * 128;
  const int bnb = blockIdx.y;
  const int tk0 = blockIdx.z * stepsPerZ;
  const int arow = tid >> 1, ahalf = tid & 1;
  const int fr = l & 15, q = l >> 4;
  const int wr = (w >> 1) * 64, wc = (w & 1) * 64;
  const int qs = q ^ (fr & 3) ^ (fr >> 2);
  const int aoff = ((wr + fr) * 4 + qs) * 16;
  const int boff = ((wc + fr) * 4 + qs) * 16;
  const float* aptr = A + (size_t)(bm + arow) * K + ahalf * 16;

  float4 av[4];
  auto loadA = [&](int tk) {
    const float* p = aptr + tk * 32;
#pragma unroll
    for (int j = 0; j < 4; ++j) av[j] = *(const float4*)(p + j * 4);
  };
  auto stageB = [&](int bf, int tk) {
    const unsigned short* gh = Bh + ((size_t)(bnb * nKB + tk)) * 4096;
    const unsigned short* gl_ = Bl + ((size_t)(bnb * nKB + tk)) * 4096;
#pragma unroll
    for (int rseg = 0; rseg < 2; ++rseg) {
      const int seg = rseg * 4 + w;
      gload16(gh + (size_t)(seg * 64 + l) * 8, &lds[bf][2][seg * 512]);
      gload16(gl_ + (size_t)(seg * 64 + l) * 8, &lds[bf][3][seg * 512]);
    }
  };
  auto writeA = [&](int bf) {
#pragma unroll
    for (int j = 0; j < 2; ++j) {
      const int s_ = ahalf * 2 + j;
      float fv[8] = {av[j * 2].x, av[j * 2].y, av[j * 2].z, av[j * 2].w,
                     av[j * 2 + 1].x, av[j * 2 + 1].y, av[j * 2 + 1].z, av[j * 2 + 1].w};
      unsigned hp[4], lp[4];
#pragma unroll
      for (int p2 = 0; p2 < 4; ++p2) {
        unsigned short h0 = rne_bf16(fv[2 * p2]), h1 = rne_bf16(fv[2 * p2 + 1]);
        float l0 = fv[2 * p2] - bf16f(h0), l1 = fv[2 * p2 + 1] - bf16f(h1);
        hp[p2] = (unsigned)h0 | ((unsigned)h1 << 16);
        lp[p2] = (unsigned)rne_bf16(l0) | ((unsigned)rne_bf16(l1) << 16);
      }
      const int chunk = arow * 4 + swz(arow, s_);
      *(uint4*)&lds[bf][0][chunk * 8] = make_uint4(hp[0], hp[1], hp[2], hp[3]);
      *(uint4*)&lds[bf][1][chunk * 8] = make_uint4(lp[0], lp[1], lp[2], lp[3]);
    }
  };

  f32x4 acc[4][4];
#pragma unroll
  for (int m = 0; m < 4; ++m)
#pragma unroll
    for (int n = 0; n < 4; ++n) acc[m][n] = (f32x4){0.f, 0.f, 0.f, 0.f};

  loadA(tk0);
  stageB(0, tk0);
  writeA(0);
  __syncthreads();
  int cur = 0;
  for (int s = 0; s < stepsPerZ; ++s) {
    const bool nx = (s + 1 < stepsPerZ);
    if (nx) { loadA(tk0 + s + 1); stageB(cur ^ 1, tk0 + s + 1); }
    const char* La = (const char*)&lds[cur][0][0];
    const char* Ll = (const char*)&lds[cur][1][0];
    const char* Lbh = (const char*)&lds[cur][2][0];
    const char* Lbl = (const char*)&lds[cur][3][0];
    bf16x8 ah[4], al[4], bh[4], bl[4];
#pragma unroll
    for (int m = 0; m < 4; ++m) {
      ah[m] = *(const bf16x8*)(La + aoff + m * 1024);
      al[m] = *(const bf16x8*)(Ll + aoff + m * 1024);
    }
#pragma unroll
    for (int n = 0; n < 4; ++n) {
      bh[n] = *(const bf16x8*)(Lbh + boff + n * 1024);
      bl[n] = *(const bf16x8*)(Lbl + boff + n * 1024);
    }
#pragma unroll
    for (int m = 0; m < 4; ++m)
#pragma unroll
      for (int n = 0; n < 4; ++n) {
        acc[m][n] = __builtin_amdgcn_mfma_f32_16x16x32_bf16(ah[m], bh[n], acc[m][n], 0, 0, 0);
        acc[m][n] = __builtin_amdgcn_mfma_f32_16x16x32_bf16(ah[m], bl[n], acc[m][n], 0, 0, 0);
        acc[m][n] = __builtin_amdgcn_mfma_f32_16x16x32_bf16(al[m], bh[n], acc[m][n], 0, 0, 0);
      }
    if (nx) writeA(cur ^ 1);
    __syncthreads();
    cur ^= 1;
  }
  float* Tz = T + (size_t)blockIdx.z * (NROWS * REP);
#pragma unroll
  for (int m = 0; m < 4; ++m) {
    const int r0 = bm + wr + m * 16 + ((l >> 4) << 2);
#pragma unroll
    for (int n = 0; n < 4; ++n) {
      const int c = bnb * 128 + wc + n * 16 + fr;
#pragma unroll
      for (int j = 0; j < 4; ++j) Tz[(size_t)(r0 + j) * REP + c] = acc[m][n][j];
    }
  }
}

// ---------------- legacy fp32 GEMM (fallback when ws is small) ----------------
__global__ __launch_bounds__(256) void gemm64(
    const float* __restrict__ A, const float* __restrict__ W,
    float* __restrict__ T, int K, int N, int kChunk) {
  __shared__ float As[32][68];
  __shared__ float Bs[32][64];
  const int tid = threadIdx.x;
  const int bm = blockIdx.x * 64, bn = blockIdx.y * 64;
  const int k0 = blockIdx.z * kChunk;
  const int tx = tid & 15, ty = tid >> 4;
  const int ar = tid >> 3;
  const int ac = (tid & 7) << 2;
  const int br = tid >> 4;
  const int bc = (tid & 15) << 2;
  float acc[4][4] = {{0.f,0.f,0.f,0.f},{0.f,0.f,0.f,0.f},{0.f,0.f,0.f,0.f},{0.f,0.f,0.f,0.f}};
  for (int kk = k0; kk < k0 + kChunk; kk += 32) {
    float4 a0 = *(const float4*)&A[(size_t)(bm + ar) * K + kk + ac];
    float4 a1 = *(const float4*)&A[(size_t)(bm + ar + 32) * K + kk + ac];
    float4 b0 = *(const float4*)&W[(size_t)(kk + br) * N + bn + bc];
    float4 b1 = *(const float4*)&W[(size_t)(kk + br + 16) * N + bn + bc];
    As[ac+0][ar] = a0.x; As[ac+1][ar] = a0.y; As[ac+2][ar] = a0.z; As[ac+3][ar] = a0.w;
    As[ac+0][ar+32] = a1.x; As[ac+1][ar+32] = a1.y; As[ac+2][ar+32] = a1.z; As[ac+3][ar+32] = a1.w;
    *(float4*)&Bs[br][bc]    = b0;
    *(float4*)&Bs[br+16][bc] = b1;
    __syncthreads();
#pragma unroll
    for (int k = 0; k < 32; ++k) {
      float4 av = *(const float4*)&As[k][ty << 2];
      float4 bv = *(const float4*)&Bs[k][tx << 2];
      float a_[4] = {av.x, av.y, av.z, av.w};
      float b_[4] = {bv.x, bv.y, bv.z, bv.w};
#pragma unroll
      for (int i = 0; i < 4; ++i)
#pragma unroll
        for (int j = 0; j < 4; ++j)
          acc[i][j] = fmaf(a_[i], b_[j], acc[i][j]);
    }
    __syncthreads();
  }
  float* Tz = T + (size_t)blockIdx.z * NROWS * REP;
#pragma unroll
  for (int i = 0; i < 4; ++i) {
    float4 v = make_float4(acc[i][0], acc[i][1], acc[i][2], acc[i][3]);
    *(float4*)&Tz[(size_t)(bm + (ty << 2) + i) * N + bn + (tx << 2)] = v;
  }
}

// ---------- fused heads: wave-per-row, coalesced Wt reads, shfl reduce, softmax+decode ----------
__global__ __launch_bounds__(256) void heads2(
    const float* __restrict__ H2, const float* __restrict__ Wt,
    const float* __restrict__ bcv, const float* __restrict__ bbv,
    const float* __restrict__ props, float* __restrict__ pb, float* __restrict__ sc) {
  const int wave = threadIdx.x >> 6, l = threadIdx.x & 63;
  const int n = blockIdx.x * 4 + wave;
  const float* h = H2 + (size_t)n * REP + l * 16;
  float4 h0 = *(const float4*)h, h1 = *(const float4*)(h + 4);
  float4 h2v = *(const float4*)(h + 8), h3 = *(const float4*)(h + 12);
  float outv[25];
#pragma unroll
  for (int o = 0; o < 25; ++o) {
    const float* wp = Wt + o * REP + l * 16;
    float4 w0 = *(const float4*)wp, w1 = *(const float4*)(wp + 4);
    float4 w2 = *(const float4*)(wp + 8), w3 = *(const float4*)(wp + 12);
    float d = h0.x * w0.x;
    d = fmaf(h0.y, w0.y, d); d = fmaf(h0.z, w0.z, d); d = fmaf(h0.w, w0.w, d);
    d = fmaf(h1.x, w1.x, d); d = fmaf(h1.y, w1.y, d); d = fmaf(h1.z, w1.z, d); d = fmaf(h1.w, w1.w, d);
    d = fmaf(h2v.x, w2.x, d); d = fmaf(h2v.y, w2.y, d); d = fmaf(h2v.z, w2.z, d); d = fmaf(h2v.w, w2.w, d);
    d = fmaf(h3.x, w3.x, d); d = fmaf(h3.y, w3.y, d); d = fmaf(h3.z, w3.z, d); d = fmaf(h3.w, w3.w, d);
#pragma unroll
    for (int m = 1; m < 64; m <<= 1) d += __shfl_xor(d, m);
    outv[o] = d + ((o < 5) ? bcv[o] : bbv[o - 5]);
  }
  const float mx = fmaxf(fmaxf(fmaxf(outv[0], outv[1]), fmaxf(outv[2], outv[3])), outv[4]);
  const float e0 = expf(outv[0] - mx), e1 = expf(outv[1] - mx), e2 = expf(outv[2] - mx);
  const float e3 = expf(outv[3] - mx), e4 = expf(outv[4] - mx);
  const float inv = 1.0f / (e0 + e1 + e2 + e3 + e4);
  const float s1 = e1 * inv, s2 = e2 * inv, s3 = e3 * inv, s4 = e4 * inv;
  const float* pr = props + (size_t)n * 4;
  const float x1 = pr[0], y1 = pr[1], x2 = pr[2], y2 = pr[3];
  const float bw = x2 - x1, bh = y2 - y1;
  const float cx = x1 + 0.5f * bw, cy = y1 + 0.5f * bh;
  const int img = n >> 9, pbase = (n & 511) << 2;
#pragma unroll
  for (int c = 1; c <= 4; ++c) {
    if (l == c - 1) {
      const float r0 = outv[5 + c * 4 + 0], r1 = outv[5 + c * 4 + 1];
      const float r2 = outv[5 + c * 4 + 2], r3 = outv[5 + c * 4 + 3];
      const float dx = r0 / 10.0f, dy = r1 / 10.0f;
      const float dw = fminf(r2 / 5.0f, BBOX_CLIP_F);
      const float dh = fminf(r3 / 5.0f, BBOX_CLIP_F);
      const float pcx = dx * bw + cx, pcy = dy * bh + cy;
      const float pw = expf(dw) * bw, ph = expf(dh) * bh;
      float bx1 = pcx - 0.5f * pw, by1 = pcy - 0.5f * ph;
      float bx2 = pcx + 0.5f * pw, by2 = pcy + 0.5f * ph;
      bx1 = fminf(fmaxf(bx1, 0.f), 800.f);
      by1 = fminf(fmaxf(by1, 0.f), 800.f);
      bx2 = fminf(fmaxf(bx2, 0.f), 800.f);
      by2 = fminf(fmaxf(by2, 0.f), 800.f);
      const int pidx = pbase + (c - 1);
      float* o = pb + (size_t)(img * NDET + pidx) * 4;
      o[0] = bx1; o[1] = by1; o[2] = bx2; o[3] = by2;
      const float smc = (c == 1) ? s1 : (c == 2) ? s2 : (c == 3) ? s3 : s4;
      sc[img * NDET + pidx] = smc;
    }
  }
}

// Per proposal row (fallback paths): 25 head outputs, softmax, decode+clip
__global__ __launch_bounds__(256) void heads_kernel(
    const float* __restrict__ H2, const float* __restrict__ Wc, const float* __restrict__ bcv,
    const float* __restrict__ Wb, const float* __restrict__ bbv,
    const float* __restrict__ props, float* __restrict__ pb, float* __restrict__ sc) {
  const int n = blockIdx.x;
  __shared__ float hrow[REP];
  __shared__ float part[25][8];
  __shared__ float outv[25];
  __shared__ float smax[5];
  const int tid = threadIdx.x;
  ((float4*)hrow)[tid] = ((const float4*)(H2 + (size_t)n * REP))[tid];
  __syncthreads();
  if (tid < 200) {
    const int o = tid >> 3, s = tid & 7;
    float a = 0.f;
    if (o < 5) {
      const float* w = Wc + o;
      for (int k = s * 128; k < s * 128 + 128; ++k) a = fmaf(hrow[k], w[(size_t)k * 5], a);
    } else {
      const float* w = Wb + (o - 5);
      for (int k = s * 128; k < s * 128 + 128; ++k) a = fmaf(hrow[k], w[(size_t)k * 20], a);
    }
    part[o][s] = a;
  }
  __syncthreads();
  if (tid < 25) {
    float a = ((part[tid][0] + part[tid][1]) + (part[tid][2] + part[tid][3]))
            + ((part[tid][4] + part[tid][5]) + (part[tid][6] + part[tid][7]));
    a += (tid < 5) ? bcv[tid] : bbv[tid - 5];
    outv[tid] = a;
  }
  __syncthreads();
  if (tid == 0) {
    float m = outv[0];
    for (int c = 1; c < 5; ++c) m = fmaxf(m, outv[c]);
    float e[5], ssum = 0.f;
    for (int c = 0; c < 5; ++c) { e[c] = expf(outv[c] - m); ssum += e[c]; }
    for (int c = 0; c < 5; ++c) smax[c] = e[c] / ssum;
  }
  __syncthreads();
  if (tid < 4) {
    const int c = tid + 1;
    const float* pr = props + (size_t)n * 4;
    const float x1 = pr[0], y1 = pr[1], x2 = pr[2], y2 = pr[3];
    const float w = x2 - x1, h = y2 - y1;
    const float cx = x1 + 0.5f * w, cy = y1 + 0.5f * h;
    const float r0 = outv[5 + c * 4 + 0], r1 = outv[5 + c * 4 + 1];
    const float r2 = outv[5 + c * 4 + 2], r3 = outv[5 + c * 4 + 3];
    const float dx = r0 / 10.0f, dy = r1 / 10.0f;
    const float dw = fminf(r2 / 5.0f, BBOX_CLIP_F);
    const float dh = fminf(r3 / 5.0f, BBOX_CLIP_F);
    const float pcx = dx * w + cx, pcy = dy * h + cy;
    const float pw = expf(dw) * w, ph = expf(dh) * h;
    float bx1 = pcx - 0.5f * pw, by1 = pcy - 0.5f * ph;
    float bx2 = pcx + 0.5f * pw, by2 = pcy + 0.5f * ph;
    bx1 = fminf(fmaxf(bx1, 0.f), 800.f);
    by1 = fminf(fmaxf(by1, 0.f), 800.f);
    bx2 = fminf(fmaxf(bx2, 0.f), 800.f);
    by2 = fminf(fmaxf(by2, 0.f), 800.f);
    const int img = n >> 9;
    const int pidx = ((n & 511) << 2) + (c - 1);
    float* o = pb + (size_t)(img * NDET + pidx) * 4;
    o[0] = bx1; o[1] = by1; o[2] = bx2; o[3] = by2;
    sc[img * NDET + pidx] = smax[c];
  }
}

// ---------- fused: stable descending bitonic sort + prep (gather, valid bits, offsets) ----------
__global__ __launch_bounds__(1024) void sortprep_kernel(
    const float* __restrict__ sc, const float* __restrict__ pb,
    float* __restrict__ sbox, float* __restrict__ soff, float* __restrict__ sscore,
    float* __restrict__ sarea, float* __restrict__ slab, unsigned* __restrict__ vword) {
  const int b = blockIdx.x;
  __shared__ unsigned long long key[NDET];
  const int tid = threadIdx.x;
  for (int t = tid; t < NDET; t += 1024) {
    unsigned bits = __float_as_uint(sc[b * NDET + t]);   // scores > 0 -> monotonic
    key[t] = ((unsigned long long)bits << 32) | (unsigned)(~t);
  }
  __syncthreads();
  for (int k = 2; k <= NDET; k <<= 1) {
    for (int j = k >> 1; j > 0; j >>= 1) {
      for (int t = tid; t < NDET; t += 1024) {
        const int ixj = t ^ j;
        if (ixj > t) {
          const bool up = (t & k) == 0;
          unsigned long long a = key[t], bb_ = key[ixj];
          if ((a < bb_) == up) { key[t] = bb_; key[ixj] = a; }
        }
      }
      __syncthreads();
    }
  }
  for (int pass = 0; pass < 2; ++pass) {
    const int i = pass * 1024 + tid;
    const unsigned oi = ~(unsigned)key[i];
    const float* bx = pb + (size_t)(b * NDET + oi) * 4;
    const float x1 = bx[0], y1 = bx[1], x2 = bx[2], y2 = bx[3];
    const float s = sc[b * NDET + oi];
    const float lab = (float)((oi & 3) + 1);
    const bool valid = (s > 0.05f) && ((x2 - x1) >= 0.01f) && ((y2 - y1) >= 0.01f);
    const float off = lab * 801.0f;
    float* sb = sbox + (size_t)(b * NDET + i) * 4;
    sb[0] = x1; sb[1] = y1; sb[2] = x2; sb[3] = y2;
    float* so = soff + (size_t)(b * NDET + i) * 4;
    so[0] = x1 + off; so[1] = y1 + off; so[2] = x2 + off; so[3] = y2 + off;
    sscore[b * NDET + i] = s;
    sarea[b * NDET + i] = (x2 - x1) * (y2 - y1);
    slab[b * NDET + i] = lab;
    const unsigned long long bal = __ballot(valid);
    if ((i & 31) == 0) vword[b * 64 + (i >> 5)] = (unsigned)(bal >> (i & 32));
  }
}

// Suppression bitmask, CONTIGUOUS layout: word w of row i covers rows [w*32, w*32+32)
__global__ __launch_bounds__(256) void mask_kernel(
    const float* __restrict__ soff, const float* __restrict__ sarea,
    unsigned* __restrict__ mask) {
  const int b = blockIdx.y;
  __shared__ float xx1[NDET + 64], yy1[NDET + 64], xx2[NDET + 64], yy2[NDET + 64];
  __shared__ float ar[NDET + 64];
  const int tid = threadIdx.x;
  for (int t = tid; t < NDET; t += 256) {
    float4 v = *(const float4*)(soff + ((size_t)b * NDET + t) * 4);
    const int pt = t + (t >> 5);
    xx1[pt] = v.x; yy1[pt] = v.y; xx2[pt] = v.z; yy2[pt] = v.w;
    ar[pt] = sarea[b * NDET + t];
  }
  __syncthreads();
  const int li = tid >> 6;
  const int w  = tid & 63;
#pragma unroll
  for (int pass = 0; pass < 4; ++pass) {
    const int i = blockIdx.x * 16 + pass * 4 + li;
    const int pi = i + (i >> 5);
    const float ax1 = xx1[pi], ay1 = yy1[pi], ax2 = xx2[pi], ay2 = yy2[pi];
    const float aa = ar[pi];
    unsigned bits = 0;
#pragma unroll 4
    for (int bb = 0; bb < 32; ++bb) {
      const int j = w * 32 + bb;
      const int pj = w * 33 + bb;
      const float ix = fmaxf(fminf(ax2, xx2[pj]) - fmaxf(ax1, xx1[pj]), 0.f);
      const float iy = fmaxf(fminf(ay2, yy2[pj]) - fmaxf(ay1, yy1[pj]), 0.f);
      const float inter = ix * iy;
      const float iou = inter / (aa + ar[pj] - inter + 1e-9f);
      if (j > i && iou > 0.5f) bits |= (1u << bb);
    }
    mask[((size_t)b * NDET + i) * 64 + w] = bits;
  }
}

// Greedy NMS scan: suppression word in REGISTER per lane; shfl (no LDS/barrier) per keep.
__global__ __launch_bounds__(64) void scan_kernel(
    const unsigned* __restrict__ vword, const unsigned* __restrict__ mask,
    const float* __restrict__ sbox, const float* __restrict__ sscore,
    const float* __restrict__ slab, float* __restrict__ out) {
  const int b = blockIdx.x;
  const int lane = threadIdx.x;
  unsigned supreg = ~vword[b * 64 + lane];   // invalid rows pre-suppressed
  __shared__ unsigned short klist[DETS];
  int kcnt = 0;
  for (int w = 0; w < 64 && kcnt < DETS; ++w) {
    unsigned avail = ~__shfl(supreg, w);
    while (avail) {
      const int bb = __ffs(avail) - 1;
      const int i = w * 32 + bb;
      if (lane == 0) klist[kcnt] = (unsigned short)i;
      kcnt++;
      if (kcnt == DETS) break;
      supreg |= mask[((size_t)b * NDET + i) * 64 + lane];
      avail = ~__shfl(supreg, w) & (0xFFFFFFFEu << bb);
    }
  }
  __syncthreads();
  for (int s = lane; s < DETS; s += 64) {
    float b0 = 0.f, b1 = 0.f, b2 = 0.f, b3 = 0.f, sv = 0.f, lv = 0.f;
    if (s < kcnt) {
      const int i = klist[s];
      const float* bx = sbox + ((size_t)b * NDET + i) * 4;
      b0 = bx[0]; b1 = bx[1]; b2 = bx[2]; b3 = bx[3];
      sv = sscore[b * NDET + i];
      lv = slab[b * NDET + i];
    }
    float* ob = out + ((size_t)b * DETS + s) * 4;
    ob[0] = b0; ob[1] = b1; ob[2] = b2; ob[3] = b3;
    out[2 * DETS * 4 + b * DETS + s] = sv;
    out[2 * DETS * 4 + 2 * DETS + b * DETS + s] = lv;
  }
}

extern "C" void kernel_launch(void* const* d_in, const int* in_sizes, int n_in,
                              void* d_out, int out_size, void* d_ws, size_t ws_size,
                              hipStream_t stream) {
  const float* X     = (const float*)d_in[0];
  const float* props = (const float*)d_in[1];
  const float* W1    = (const float*)d_in[2];
  const float* b1    = (const float*)d_in[3];
  const float* W2    = (const float*)d_in[4];
  const float* b2    = (const float*)d_in[5];
  const float* Wc    = (const float*)d_in[6];
  const float* bc    = (const float*)d_in[7];
  const float* Wb    = (const float*)d_in[8];
  const float* bb    = (const float*)d_in[9];
  float* out = (float*)d_out;

  const size_t POST_B = 3200000;
  const size_t NEED_BIG =
      (size_t)9 * 1048576 * 4 +
      (size_t)4 * (size_t)K1 * 1024 * 2 +
      (size_t)4 * 1048576 * 2 + POST_B;
  const size_t NEED_MID =
      (size_t)10 * 1048576 * 4 +
      (size_t)2 * (size_t)K1 * 1024 * 2 +
      (size_t)2 * 1048576 * 2 + 2500000;

  float *T, *H1 = nullptr, *H2, *pb, *sc, *Wt = nullptr;
  unsigned short *W1h = nullptr, *W1l = nullptr, *W2h = nullptr, *W2l = nullptr;
  unsigned short *Ahp = nullptr, *Alp = nullptr, *H1h = nullptr, *H1l = nullptr;
  const int path = (ws_size >= NEED_BIG) ? 2 : (ws_size >= NEED_MID) ? 1 : 0;
  if (path == 2) {
    T   = (float*)d_ws;                  // 8 * 1048576
    H2  = T + 8 * 1048576;
    W1h = (unsigned short*)(H2 + 1048576);
    W1l = W1h + (size_t)K1 * 1024;
    W2h = W1l + (size_t)K1 * 1024;
    W2l = W2h + 1048576;
    Ahp = W2l + 1048576;
    Alp = Ahp + (size_t)K1 * 1024;
    H1h = Alp + (size_t)K1 * 1024;
    H1l = H1h + 1048576;
    Wt  = (float*)(H1l + 1048576);       // 25*1024 floats
    pb  = Wt + 25 * 1024;
  } else if (path == 1) {
    T   = (float*)d_ws;
    H1  = T + 8 * 1048576;
    H2  = H1 + 1048576;
    W1h = (unsigned short*)(H2 + 1048576);
    W1l = W1h + (size_t)K1 * 1024;
    W2h = W1l + (size_t)K1 * 1024;
    W2l = W2h + 1048576;
    pb  = (float*)(W2l + 1048576);
  } else {
    T  = (float*)d_ws;
    H1 = T + 4 * 1048576;
    H2 = H1 + 1048576;
    pb = H2 + 1048576;
  }
  sc = pb + 2 * NDET * 4;
  unsigned* sidx = (unsigned*)(sc + 2 * NDET);   // kept for layout stability (unused)
  float* sbox   = (float*)(sidx + 2 * NDET);
  float* soff   = sbox + 2 * NDET * 4;
  float* sscore = soff + 2 * NDET * 4;
  float* sarea  = sscore + 2 * NDET;
  float* slab   = sarea + 2 * NDET;
  unsigned* vword = (unsigned*)(slab + 2 * NDET);
  unsigned* mask  = vword + 128;

  if (path == 2) {
    pack_fused<<<19940, 256, 0, stream>>>(X, W1, W2, Wc, Wb,
                                          Ahp, Alp, W1h, W1l, W2h, W2l, Wt);
    gemm_pk2<<<dim3(8, 8, 8), 256, 0, stream>>>(Ahp, Alp, W1h, W1l, T, K1 / 32, 49);
    combine8_relu_pack<<<512, 256, 0, stream>>>(T, b1, H1h, H1l);
    gemm_pk2<<<dim3(8, 8, 4), 256, 0, stream>>>(H1h, H1l, W2h, W2l, T, 32, 8);
    combineN_relu<<<1024, 256, 0, stream>>>(T, b2, H2, 4);
    heads2<<<256, 256, 0, stream>>>(H2, Wt, bc, bb, props, pb, sc);
  } else if (path == 1) {
    pack_b<<<dim3(K1 / 32, 32), 256, 0, stream>>>(W1, W1h, W1l, K1 / 32);
    pack_b<<<dim3(32, 32), 256, 0, stream>>>(W2, W2h, W2l, 32);
    gemm_pk<<<dim3(8, 8, 8), 256, 0, stream>>>(X, W1h, W1l, T, K1, K1 / 32, 49);
    combineN_relu<<<1024, 256, 0, stream>>>(T, b1, H1, 8);
    gemm_pk<<<dim3(8, 8, 4), 256, 0, stream>>>(H1, W2h, W2l, T, REP, 32, 8);
    combineN_relu<<<1024, 256, 0, stream>>>(T, b2, H2, 4);
    heads_kernel<<<1024, 256, 0, stream>>>(H2, Wc, bc, Wb, bb, props, pb, sc);
  } else {
    gemm64<<<dim3(16, 16, 4), 256, 0, stream>>>(X, W1, T, K1, REP, K1 / 4);
    combineN_relu<<<1024, 256, 0, stream>>>(T, b1, H1, 4);
    gemm64<<<dim3(16, 16, 4), 256, 0, stream>>>(H1, W2, T, REP, REP, REP / 4);
    combineN_relu<<<1024, 256, 0, stream>>>(T, b2, H2, 4);
    heads_kernel<<<1024, 256, 0, stream>>>(H2, Wc, bc, Wb, bb, props, pb, sc);
  }
  sortprep_kernel<<<2, 1024, 0, stream>>>(sc, pb, sbox, soff, sscore, sarea, slab, vword);
  mask_kernel<<<dim3(128, 2), 256, 0, stream>>>(soff, sarea, mask);
  scan_kernel<<<2, 64, 0, stream>>>(vword, mask, sbox, sscore, slab, out);
}